// Round 7
// baseline (526.929 us; speedup 1.0000x reference)
//
#include <hip/hip_runtime.h>

typedef _Float16 f16;
typedef _Float16 f16x8 __attribute__((ext_vector_type(8)));
typedef _Float16 f16x4 __attribute__((ext_vector_type(4)));
typedef float f32x4 __attribute__((ext_vector_type(4)));

#define NCAM 6
#define CINF 512
#define MIDC 256
#define DB   112
#define HH   32
#define WW   88
#define PH   34
#define PW   90
#define NPOS (HH*WW)       /* 2816 */

// ---- workspace layout (bytes) ----
#define O_GATE   0L
#define O_WFRED  6144L
#define O_LOG    6144L        /* overlays WfRed+WfBB; written only after all f16 convs done */
#define O_WFBB   2365440L
#define O_WFDP   9443328L
#define O_XP0    9508864L
#define O_X1     28309504L
#define O_DP     28309504L    /* overlays X1; written only after X1's last read */
#define O_X2     37709824L
#define O_X3     47110144L
/* end: 56510464 (< 71.6MB known-good ws) */

__device__ __forceinline__ void gl_lds16(const void* g, void* l) {
  __builtin_amdgcn_global_load_lds((const __attribute__((address_space(1))) void*)g,
                                   (__attribute__((address_space(3))) void*)l, 16, 0, 0);
}

// ---------------- halo-only zeroing of the 4 padded NHWC buffers ----------------
__global__ void halo_zero_kernel(f16* __restrict__ xp0, f16* __restrict__ X1,
                                 f16* __restrict__ X2, f16* __restrict__ X3) {
  int idx = blockIdx.x * 256 + threadIdx.x;       // one 16B chunk each
  f16* base; int C, rem;
  if (idx < 93696) { base = xp0; C = 512; rem = idx; }
  else {
    int k = idx - 93696;
    int bsel = k / 46848;
    if (bsel >= 3) return;
    rem = k - bsel * 46848; C = 256;
    base = (bsel == 0) ? X1 : (bsel == 1) ? X2 : X3;
  }
  int chunks = C >> 3;
  int cell = rem / chunks, cc = rem - cell * chunks;
  int cam = cell / 244, p = cell - cam * 244;
  int hh, ww;
  if (p < 90)       { hh = 0;  ww = p; }
  else if (p < 180) { hh = 33; ww = p - 90; }
  else { int q = p - 180; hh = 1 + (q >> 1); ww = (q & 1) * 89; }
  long o = ((long)(cam * PH + hh) * PW + ww) * C + cc * 8;
  f16x8 z = {0,0,0,0,0,0,0,0};
  *(f16x8*)(base + o) = z;
}

// ---------------- weights -> MFMA A-fragment order, scale folded ----------------
// dst idx = (((g*TAPS+tap)*KST+ks)<<11) + (mi<<9) + (lane<<3) + j
// co = g*64+mi*16+(lane&15), ci = ks*32+(lane>>4)*8+j, src OIHW[co][ci][tap]
__global__ void wfrag_kernel(const float* __restrict__ src, const float* __restrict__ scale,
                             f16* __restrict__ dst, int NC, int G, int TAPS, int CI, int CO_SRC,
                             long per, long total) {
  long i = (long)blockIdx.x * blockDim.x + threadIdx.x;
  long stride = (long)gridDim.x * blockDim.x;
  int KST = CI >> 5;
  for (; i < total; i += stride) {
    int conv = (int)(i / per);
    long rem = i - (long)conv * per;
    int j = (int)(rem & 7);
    int lane = (int)((rem >> 3) & 63);
    int mi = (int)((rem >> 9) & 3);
    long b = rem >> 11;
    int ks = (int)(b % KST);
    long b2 = b / KST;
    int tap = (int)(b2 % TAPS);
    int g = (int)(b2 / TAPS);
    int co = g * 64 + mi * 16 + (lane & 15);
    int ci = ks * 32 + (lane >> 4) * 8 + j;
    float v = 0.f;
    if (co < CO_SRC) {
      v = src[(long)conv * CO_SRC * CI * TAPS + ((long)co * CI + ci) * TAPS + tap];
      if (scale) v *= scale[conv * CO_SRC + co];
    }
    dst[i] = (f16)v;
  }
}

// ---------------- img NCHW f32 -> padded NHWC f16 ----------------
__global__ void img_trans_kernel(const float* __restrict__ src, f16* __restrict__ dst) {
  __shared__ float tile[32][33];
  int tx = threadIdx.x & 31, ty = threadIdx.x >> 5;
  int wt = blockIdx.x % 3, ct = blockIdx.x / 3;
  int h = blockIdx.y, n = blockIdx.z;
  int w0 = wt * 32, c0 = ct * 32;
  #pragma unroll
  for (int i = 0; i < 4; ++i) {
    int cl = ty + i * 8;
    int w = w0 + tx;
    float v = 0.f;
    if (w < WW) v = src[((long)(n * CINF + c0 + cl) * HH + h) * WW + w];
    tile[cl][tx] = v;
  }
  __syncthreads();
  #pragma unroll
  for (int i = 0; i < 4; ++i) {
    int wl = ty + i * 8;
    int w = w0 + wl;
    if (w < WW)
      dst[((long)((n * PH + h + 1) * PW + (w + 1))) * CINF + c0 + tx] = (f16)tile[tx][wl];
  }
}

// ---------------- SE gate ----------------
__global__ void se_gate_kernel(const float* __restrict__ intr,
                               const float* __restrict__ w1, const float* __restrict__ b1,
                               const float* __restrict__ w2, const float* __restrict__ b2,
                               const float* __restrict__ rw, const float* __restrict__ rb,
                               const float* __restrict__ ew, const float* __restrict__ eb,
                               float* __restrict__ gate) {
  __shared__ float sps;
  __shared__ float h1[MIDC];
  __shared__ float h2[MIDC];
  __shared__ float tt[MIDC];
  int n = blockIdx.x, c = threadIdx.x;
  if (c == 0) {
    float a[4][8];
    for (int i = 0; i < 4; ++i)
      for (int j = 0; j < 4; ++j) {
        a[i][j] = intr[n * 16 + i * 4 + j];
        a[i][4 + j] = (i == j) ? 1.f : 0.f;
      }
    for (int col = 0; col < 4; ++col) {
      int piv = col;
      for (int r2 = col + 1; r2 < 4; ++r2)
        if (fabsf(a[r2][col]) > fabsf(a[piv][col])) piv = r2;
      if (piv != col)
        for (int j = 0; j < 8; ++j) { float tv = a[col][j]; a[col][j] = a[piv][j]; a[piv][j] = tv; }
      float invp = 1.f / a[col][col];
      for (int j = 0; j < 8; ++j) a[col][j] *= invp;
      for (int r2 = 0; r2 < 4; ++r2)
        if (r2 != col) {
          float f = a[r2][col];
          for (int j = 0; j < 8; ++j) a[r2][j] -= f * a[col][j];
        }
    }
    float i00 = a[0][4], i11 = a[1][5];
    sps = sqrtf(i00 * i00 + i11 * i11) * 1000.f;
  }
  __syncthreads();
  float sp = sps;
  h1[c] = fmaxf(sp * w1[c] + b1[c], 0.f);
  __syncthreads();
  float acc = b2[c];
  for (int j = 0; j < MIDC; ++j) acc += h1[j] * w2[j * MIDC + c];
  h2[c] = acc;
  __syncthreads();
  acc = rb[c];
  for (int j = 0; j < MIDC; ++j) acc += rw[c * MIDC + j] * h2[j];
  tt[c] = fmaxf(acc, 0.f);
  __syncthreads();
  acc = eb[c];
  for (int j = 0; j < MIDC; ++j) acc += ew[c * MIDC + j] * tt[j];
  gate[n * MIDC + c] = 1.f / (1.f + expf(-acc));
}

// ---------------- MFMA implicit-GEMM conv, 64x64 wave tile ----------------
// Rounds 0-6 invariant: interval ~2100cy/chunk at MfmaUtil 26%, unaffected by occupancy,
// fetch locality, or pipeline depth -> per-chunk LDS traffic + barrier overhead per FLOP
// is the binding constraint. Fix: wave tile 64co x 64/72pos (FLOP per LDS byte
// co*pos/(co+pos): 21.3 -> 32+), block 128co x {128,144}pos, grid EXACTLY 256
// (2 co-interleaved panels x 128 pos-blocks; per cam: cams 0-1 = 22x128, cams 2-5 =
// 13x128 + 8x144 -> no block crosses a camera; fat/thin makespan ratio 1.125).
// Keeps: co_tile=bid%co_tiles interleave (19MB FETCH floor), XCD swizzle (T1, grids %8==0),
// round-4 __syncthreads double-buffer loop (== counted-vmcnt, measured r6).
// MODE 0: relu(acc+b)*gate   MODE 1: relu(acc+b)   MODE 2: relu(acc+b+res)   MODE 3: acc+b -> f32
template<int MODE, int CIN_T, int TAPS>
__global__ __launch_bounds__(256)
void conv_mfma(const f16* __restrict__ X, const f16* __restrict__ Wf,
               const float* __restrict__ bias, const float* __restrict__ gate,
               const f16* __restrict__ res, f16* __restrict__ Yf16,
               float* __restrict__ Yf32, int co_tiles) {
  constexpr int KST = CIN_T / 32;
  constexpr int CPT = CIN_T / 64;
  constexpr int NCH = TAPS * CPT;
  constexpr int LCPT = (CPT == 8) ? 3 : 2;
  constexpr long GSTR = (long)TAPS * KST * 4096;   // bytes per weight group
  constexpr int BSTR = 34816;                      // 16KB A + 18KB B (max)
  __shared__ __align__(16) char S[2 * BSTR];

  const int t = threadIdx.x;
  const int wv = t >> 6, ln = t & 63, lm = ln & 15, quad = ln >> 4;
  const int wm = wv >> 1, wn = wv & 1;
  // XCD-aware swizzle: bid0%8 is the XCD; give each XCD a contiguous bid range.
  const int bid0 = blockIdx.x;
  const int cpx = gridDim.x >> 3;                  // grids are %8 == 0
  const int bid = (bid0 & 7) * cpx + (bid0 >> 3);
  const int co_tile = bid % co_tiles;
  const int r = bid / co_tiles;                    // 0..127 pos-block index
  // per-camera pos decomposition: cams 0,1: 22x128; cams 2..5: 13x128 + 8x144
  int cam, p0, nrows;
  if (r < 44) { cam = r / 22; p0 = (r % 22) * 128; nrows = 128; }
  else {
    int rr = r - 44;
    cam = 2 + rr / 21;
    int q = rr % 21;
    if (q < 13) { p0 = q * 128; nrows = 128; }
    else        { p0 = 1664 + (q - 13) * 144; nrows = 144; }
  }
  const int ntk = nrows >> 4;                      // 8 or 9 pos-tiles of 16
  const int nregs = nrows >> 3;                    // 16 or 18 B staging segments
  const int nti = (ntk + 1 - wn) >> 1;             // tiles/wave: {4,4} or {5,4}

  // B DMA setup: up to 5 instrs/wave, each covers 8 rows x 8 phys chunks
  const f16* gB[5];
  const int clog = (ln & 7) ^ (ln >> 3);
  #pragma unroll
  for (int j = 0; j < 5; ++j) {
    int seg = j * 4 + wv;
    int pl = p0 + seg * 8 + (ln >> 3);             // cam-local; guarded at issue
    int hh = pl / WW, w2 = pl - hh * WW;
    gB[j] = X + ((long)((cam * PH + hh + 1) * PW + (w2 + 1))) * CIN_T + clog * 8;
  }

  // lane-constant bf swizzled column offsets (bytes)
  const int sx0 = ((0 * 4 + quad) ^ (lm & 7)) * 16;
  const int sx1 = ((1 * 4 + quad) ^ (lm & 7)) * 16;

  f32x4 acc[4][5];
  #pragma unroll
  for (int mi = 0; mi < 4; ++mi)
    #pragma unroll
    for (int i = 0; i < 5; ++i)
      #pragma unroll
      for (int q = 0; q < 4; ++q) acc[mi][i][q] = 0.f;

  auto choff = [&](int c) -> long {
    long off = 0;
    if (TAPS == 9) {
      int tp = c >> LCPT;
      int dy = tp / 3 - 1, dx = tp % 3 - 1;
      off = (long)(dy * PW + dx) * CIN_T;
    }
    return off + (long)(c & (CPT - 1)) * 64;
  };
  // stage one chunk: A (16KB: 2 groups x 8KB) + B (nrows x 128B)
  auto stage = [&](int bsel, int c) {
    char* db = S + bsel * BSTR;
    const char* sb = (const char*)Wf + (long)c * 8192 + (long)ln * 16;
    #pragma unroll
    for (int j = 0; j < 4; ++j) {
      int seg = j * 4 + wv;                       // 0..15 (1KB segments)
      long gb = (long)(co_tile * 2 + (seg >> 3)) * GSTR;
      gl_lds16(sb + gb + (seg & 7) * 1024, db + seg * 1024);
    }
    long curf = choff(c);
    #pragma unroll
    for (int j = 0; j < 5; ++j) {
      int seg = j * 4 + wv;
      if (seg < nregs)                            // wave-uniform predicate
        gl_lds16(gB[j] + curf, db + 16384 + seg * 1024);
    }
  };
  auto compute = [&](int bsel) {
    const char* ab = S + bsel * BSTR + wm * 8192 + ln * 16;
    const char* bb = S + bsel * BSTR + 16384 + lm * 128;
    #pragma unroll
    for (int s = 0; s < 2; ++s) {
      f16x8 af[4];
      #pragma unroll
      for (int mi = 0; mi < 4; ++mi)
        af[mi] = *(const f16x8*)(ab + s * 4096 + mi * 1024);
      int sx = s ? sx1 : sx0;
      #pragma unroll
      for (int i = 0; i < 5; ++i) {
        if (i < nti) {
          f16x8 bf = *(const f16x8*)(bb + (2 * i + wn) * 2048 + sx);
          #pragma unroll
          for (int mi = 0; mi < 4; ++mi)
            acc[mi][i] = __builtin_amdgcn_mfma_f32_16x16x32_f16(af[mi], bf, acc[mi][i], 0, 0, 0);
        }
      }
    }
  };

  stage(0, 0);
  __syncthreads();

  #pragma unroll 1
  for (int c = 0; c < NCH; ++c) {
    int cur = c & 1;
    if (c + 1 < NCH) stage(cur ^ 1, c + 1);
    compute(cur);
    __syncthreads();
  }

  // ---- epilogue: direct stores from acc ----
  float4 b4[4], g4[4];
  bool skip[4];
  #pragma unroll
  for (int mi = 0; mi < 4; ++mi) {
    int co_l = wm * 64 + mi * 16 + quad * 4;
    int co_g = co_tile * 128 + co_l;
    skip[mi] = (MODE == 3) && (co_l >= DB);
    if (!skip[mi]) b4[mi] = *(const float4*)(bias + co_g);
    if (MODE == 0) g4[mi] = *(const float4*)(gate + cam * MIDC + co_g);
  }
  #pragma unroll
  for (int i = 0; i < 5; ++i) {
    if (i >= nti) continue;
    int k = 2 * i + wn;
    int pos_l = p0 + k * 16 + lm;
    long ob;
    if (MODE == 3) ob = ((long)(cam * NPOS + pos_l)) * DB;
    else {
      int hh = pos_l / WW, w2 = pos_l - hh * WW;
      ob = ((long)((cam * PH + hh + 1) * PW + (w2 + 1))) * MIDC + co_tile * 128;
    }
    #pragma unroll
    for (int mi = 0; mi < 4; ++mi) {
      if (skip[mi]) continue;
      int co_l = wm * 64 + mi * 16 + quad * 4;
      float v[4];
      #pragma unroll
      for (int q = 0; q < 4; ++q) {
        float y = acc[mi][i][q];
        y += ((float*)&b4[mi])[q];
        if (MODE == 0) y = fmaxf(y, 0.f) * ((float*)&g4[mi])[q];
        else if (MODE == 1) y = fmaxf(y, 0.f);
        v[q] = y;
      }
      if (MODE == 3) {
        float4 o; o.x = v[0]; o.y = v[1]; o.z = v[2]; o.w = v[3];
        *(float4*)(Yf32 + ob + co_l) = o;
      } else if (MODE == 2) {
        f16x4 rv = *(const f16x4*)(res + ob + co_l);
        f16x4 o;
        #pragma unroll
        for (int q = 0; q < 4; ++q) o[q] = (f16)fmaxf(v[q] + (float)rv[q], 0.f);
        *(f16x4*)(Yf16 + ob + co_l) = o;
      } else {
        f16x4 o;
        #pragma unroll
        for (int q = 0; q < 4; ++q) o[q] = (f16)v[q];
        *(f16x4*)(Yf16 + ob + co_l) = o;
      }
    }
  }
}

// ---------------- softmax over 112 bins, one wave per position ----------------
__global__ void softmax_kernel(const float* __restrict__ L, float* __restrict__ dp) {
  int wid = (int)(((long)blockIdx.x * blockDim.x + threadIdx.x) >> 6);
  int lane = threadIdx.x & 63;
  if (wid >= NCAM * NPOS) return;
  const float* lp = L + (long)wid * DB;
  float v0 = -1e30f, v1 = -1e30f;
  if (lane < 56) { v0 = lp[lane * 2]; v1 = lp[lane * 2 + 1]; }
  float m = fmaxf(v0, v1);
  #pragma unroll
  for (int o = 32; o; o >>= 1) m = fmaxf(m, __shfl_xor(m, o));
  float e0 = 0.f, e1 = 0.f;
  if (lane < 56) { e0 = __expf(v0 - m); e1 = __expf(v1 - m); }
  float ssum = e0 + e1;
  #pragma unroll
  for (int o = 32; o; o >>= 1) ssum += __shfl_xor(ssum, o);
  float inv = 1.f / ssum;
  if (lane < 56) {
    float2 r; r.x = e0 * inv; r.y = e1 * inv;
    *(float2*)(dp + (long)wid * DB + lane * 2) = r;
  }
}

// ---------------- trilinear grid sample + camera sum + normalize ----------------
__global__ void sample_kernel(const float* __restrict__ grid, const float* __restrict__ dp,
                              float* __restrict__ out) {
  int v = blockIdx.x * blockDim.x + threadIdx.x;
  if (v >= 128 * 128 * 16) return;
  int vz = v & 15, vy = (v >> 4) & 127, vx = v >> 11;
  float agg = 0.f, msk = 0.f;
  #pragma unroll 1
  for (int n = 0; n < NCAM; ++n) {
    long gb = ((long)((n * 128 + vx) * 128 + vy) * 16 + vz) * 3;
    float gx = grid[gb], gy = grid[gb + 1], gz = grid[gb + 2];
    float ix = ((gx + 1.f) * (float)WW - 1.f) * 0.5f;
    float iy = ((gy + 1.f) * (float)HH - 1.f) * 0.5f;
    float iz = ((gz + 1.f) * (float)DB - 1.f) * 0.5f;
    float xf = floorf(ix), yf = floorf(iy), zf = floorf(iz);
    float fx = ix - xf, fy = iy - yf, fz = iz - zf;
    int x0 = (int)xf, y0 = (int)yf, z0 = (int)zf;
    float wxa[2] = {1.f - fx, fx};
    float wya[2] = {1.f - fy, fy};
    float wza[2] = {1.f - fz, fz};
    #pragma unroll
    for (int dy2 = 0; dy2 < 2; ++dy2) {
      int y = y0 + dy2;
      bool vyb = (y >= 0) && (y < HH);
      int yc = y < 0 ? 0 : (y > HH - 1 ? HH - 1 : y);
      #pragma unroll
      for (int dx2 = 0; dx2 < 2; ++dx2) {
        int x = x0 + dx2;
        bool vxb = (x >= 0) && (x < WW);
        int xc = x < 0 ? 0 : (x > WW - 1 ? WW - 1 : x);
        float wxy = wxa[dx2] * wya[dy2];
        const float* base = dp + ((long)((n * HH + yc) * WW + xc)) * DB;
        #pragma unroll
        for (int dz2 = 0; dz2 < 2; ++dz2) {
          int z = z0 + dz2;
          bool vzb = (z >= 0) && (z < DB);
          int zc = z < 0 ? 0 : (z > DB - 1 ? DB - 1 : z);
          float wgt = wxy * wza[dz2];
          if (vxb && vyb && vzb) {
            msk += wgt;
            agg += wgt * base[zc];
          }
        }
      }
    }
  }
  out[v] = (msk > 0.f) ? (agg / msk) : agg;
}

extern "C" void kernel_launch(void* const* d_in, const int* in_sizes, int n_in,
                              void* d_out, int out_size, void* d_ws, size_t ws_size,
                              hipStream_t stream) {
  const float* img   = (const float*)d_in[0];
  const float* intr  = (const float*)d_in[1];
  const float* grid  = (const float*)d_in[2];
  const float* red_w = (const float*)d_in[3];
  const float* red_s = (const float*)d_in[4];
  const float* red_b = (const float*)d_in[5];
  const float* w1    = (const float*)d_in[6];
  const float* b1    = (const float*)d_in[7];
  const float* w2    = (const float*)d_in[8];
  const float* b2    = (const float*)d_in[9];
  const float* rw    = (const float*)d_in[10];
  const float* rb    = (const float*)d_in[11];
  const float* ew    = (const float*)d_in[12];
  const float* eb    = (const float*)d_in[13];
  const float* bb_w  = (const float*)d_in[14];
  const float* bb_s  = (const float*)d_in[15];
  const float* bb_b  = (const float*)d_in[16];
  const float* dp_w  = (const float*)d_in[17];
  const float* dp_b  = (const float*)d_in[18];
  float* out = (float*)d_out;

  char* ws = (char*)d_ws;
  float* gate = (float*)(ws + O_GATE);
  f16* wfred  = (f16*)(ws + O_WFRED);
  f16* wfbb   = (f16*)(ws + O_WFBB);
  f16* wfdp   = (f16*)(ws + O_WFDP);
  f16* xp0    = (f16*)(ws + O_XP0);
  f16* X1     = (f16*)(ws + O_X1);
  f16* X2     = (f16*)(ws + O_X2);
  f16* X3     = (f16*)(ws + O_X3);
  float* Lg   = (float*)(ws + O_LOG);
  float* dpb  = (float*)(ws + O_DP);

  halo_zero_kernel<<<915, 256, 0, stream>>>(xp0, X1, X2, X3);
  {
    long per = 4L * 9 * 16 * 2048, total = per;
    wfrag_kernel<<<2048, 256, 0, stream>>>(red_w, red_s, wfred, 1, 4, 9, 512, 256, per, total);
  }
  {
    long per = 4L * 9 * 8 * 2048, total = 6 * per;
    wfrag_kernel<<<4096, 256, 0, stream>>>(bb_w, bb_s, wfbb, 6, 4, 9, 256, 256, per, total);
  }
  {
    long per = 2L * 1 * 8 * 2048, total = per;
    wfrag_kernel<<<128, 256, 0, stream>>>(dp_w, nullptr, wfdp, 1, 2, 1, 256, 112, per, total);
  }
  img_trans_kernel<<<dim3(48, 32, 6), 256, 0, stream>>>(img, xp0);
  se_gate_kernel<<<6, 256, 0, stream>>>(intr, w1, b1, w2, b2, rw, rb, ew, eb, gate);

  const long WCH = 4L * 9 * 8 * 2048;  // per-conv fragment-weight stride (f16)

  conv_mfma<0, 512, 9><<<256, 256, 0, stream>>>(xp0, wfred, red_b, gate, nullptr, X1, nullptr, 2);

  conv_mfma<1, 256, 9><<<256, 256, 0, stream>>>(X1, wfbb + 0 * WCH, bb_b + 0 * 256, nullptr, nullptr, X2, nullptr, 2);
  conv_mfma<2, 256, 9><<<256, 256, 0, stream>>>(X2, wfbb + 1 * WCH, bb_b + 1 * 256, nullptr, X1, X3, nullptr, 2);
  conv_mfma<1, 256, 9><<<256, 256, 0, stream>>>(X3, wfbb + 2 * WCH, bb_b + 2 * 256, nullptr, nullptr, X2, nullptr, 2);
  conv_mfma<2, 256, 9><<<256, 256, 0, stream>>>(X2, wfbb + 3 * WCH, bb_b + 3 * 256, nullptr, X3, X1, nullptr, 2);
  conv_mfma<1, 256, 9><<<256, 256, 0, stream>>>(X1, wfbb + 4 * WCH, bb_b + 4 * 256, nullptr, nullptr, X2, nullptr, 2);
  conv_mfma<2, 256, 9><<<256, 256, 0, stream>>>(X2, wfbb + 5 * WCH, bb_b + 5 * 256, nullptr, X1, X3, nullptr, 2);

  conv_mfma<3, 256, 1><<<128, 256, 0, stream>>>(X3, wfdp, dp_b, nullptr, nullptr, nullptr, Lg, 1);

  softmax_kernel<<<4224, 256, 0, stream>>>(Lg, dpb);
  sample_kernel<<<1024, 256, 0, stream>>>(grid, dpb, out);
}

// Round 8
// 507.163 us; speedup vs baseline: 1.0390x; 1.0390x over previous
//
#include <hip/hip_runtime.h>

typedef _Float16 f16;
typedef _Float16 f16x8 __attribute__((ext_vector_type(8)));
typedef _Float16 f16x4 __attribute__((ext_vector_type(4)));
typedef float f32x4 __attribute__((ext_vector_type(4)));

#define NCAM 6
#define CINF 512
#define MIDC 256
#define DB   112
#define HH   32
#define WW   88
#define PH   34
#define PW   90
#define NPOS (HH*WW)       /* 2816 */
#define PTILE 64
#define PT_PER_CAM 44      /* 2816/64 */

// ---- workspace layout (bytes) ----
#define O_GATE   0L
#define O_WFRED  6144L
#define O_LOG    6144L        /* overlays WfRed+WfBB; written only after all f16 convs done */
#define O_WFBB   2365440L
#define O_WFDP   9443328L
#define O_XP0    9508864L
#define O_X1     28309504L
#define O_DP     28309504L    /* overlays X1; written only after X1's last read */
#define O_X2     37709824L
#define O_X3     47110144L
/* end: 56510464 (< 71.6MB known-good ws) */

__device__ __forceinline__ void gl_lds16(const void* g, void* l) {
  __builtin_amdgcn_global_load_lds((const __attribute__((address_space(1))) void*)g,
                                   (__attribute__((address_space(3))) void*)l, 16, 0, 0);
}

// ---------------- halo-only zeroing of the 4 padded NHWC buffers ----------------
__global__ void halo_zero_kernel(f16* __restrict__ xp0, f16* __restrict__ X1,
                                 f16* __restrict__ X2, f16* __restrict__ X3) {
  int idx = blockIdx.x * 256 + threadIdx.x;       // one 16B chunk each
  f16* base; int C, rem;
  if (idx < 93696) { base = xp0; C = 512; rem = idx; }
  else {
    int k = idx - 93696;
    int bsel = k / 46848;
    if (bsel >= 3) return;
    rem = k - bsel * 46848; C = 256;
    base = (bsel == 0) ? X1 : (bsel == 1) ? X2 : X3;
  }
  int chunks = C >> 3;
  int cell = rem / chunks, cc = rem - cell * chunks;
  int cam = cell / 244, p = cell - cam * 244;
  int hh, ww;
  if (p < 90)       { hh = 0;  ww = p; }
  else if (p < 180) { hh = 33; ww = p - 90; }
  else { int q = p - 180; hh = 1 + (q >> 1); ww = (q & 1) * 89; }
  long o = ((long)(cam * PH + hh) * PW + ww) * C + cc * 8;
  f16x8 z = {0,0,0,0,0,0,0,0};
  *(f16x8*)(base + o) = z;
}

// ---------------- weights -> MFMA A-fragment order, coalesced LDS-staged ----------------
// r7 post-mortem: old wfrag's src read had a 36B lane stride (tap-major innermost) ->
// ~9x line overfetch (~127MB effective for bb). New: one block per (conv, co-pair).
// Phase 1: 256 threads read the pair's contiguous 2*CI*TAPS f32 span coalesced into LDS.
// Phase 2: each thread emits 16B dst chunks (j=0..7 packed) in fragment order:
// dst idx = (((g*TAPS+tap)*KST+ks)<<11) + (mi<<9) + (lane<<3) + j,
// co = g*64+mi*16+(lane&15), ci = ks*32+(lane>>4)*8+j, scale folded.
__global__ void wfrag_kernel(const float* __restrict__ src, const float* __restrict__ scale,
                             f16* __restrict__ dst, int TAPS, int CI, int CO_SRC, int G,
                             long dstride) {
  extern __shared__ float W[];                    // 2*CI*TAPS floats (max 36KB)
  const int pairs = G * 32;
  const int pair = blockIdx.x % pairs;
  const int conv = blockIdx.x / pairs;
  const int co0 = pair * 2;
  const int span1 = CI * TAPS;
  const int span = 2 * span1;
  const float* s0 = src + ((long)conv * CO_SRC + co0) * span1;
  for (int i = threadIdx.x; i < span; i += 256) {
    int co_rel = i / span1;
    float v = 0.f;
    if (co0 + co_rel < CO_SRC) v = s0[i];
    W[i] = v;
  }
  __syncthreads();
  const int KST = CI >> 5;
  const int nchunk = 2 * TAPS * KST * 4;
  float sc[2];
  sc[0] = (scale && co0 < CO_SRC) ? scale[conv * CO_SRC + co0] : 1.f;
  sc[1] = (scale && co0 + 1 < CO_SRC) ? scale[conv * CO_SRC + co0 + 1] : 1.f;
  f16* db = dst + (long)conv * dstride;
  for (int cnk = threadIdx.x; cnk < nchunk; cnk += 256) {
    int quad = cnk & 3;
    int b = cnk >> 2;
    int ks = b % KST;
    int b2 = b / KST;
    int tap = b2 % TAPS;
    int cosel = b2 / TAPS;
    int co = co0 + cosel;
    int g = co >> 6, mi = (co >> 4) & 3, lm = co & 15;
    f16 tmp[8];
    #pragma unroll
    for (int j = 0; j < 8; ++j) {
      int ci = ks * 32 + quad * 8 + j;
      tmp[j] = (f16)(W[cosel * span1 + ci * TAPS + tap] * sc[cosel]);
    }
    long o = ((long)((g * TAPS + tap) * KST + ks) << 11) + (mi << 9) + ((quad * 16 + lm) << 3);
    *(f16x8*)(db + o) = *(const f16x8*)tmp;
  }
}

// ---------------- img NCHW f32 -> padded NHWC f16 ----------------
__global__ void img_trans_kernel(const float* __restrict__ src, f16* __restrict__ dst) {
  __shared__ float tile[32][33];
  int tx = threadIdx.x & 31, ty = threadIdx.x >> 5;
  int wt = blockIdx.x % 3, ct = blockIdx.x / 3;
  int h = blockIdx.y, n = blockIdx.z;
  int w0 = wt * 32, c0 = ct * 32;
  #pragma unroll
  for (int i = 0; i < 4; ++i) {
    int cl = ty + i * 8;
    int w = w0 + tx;
    float v = 0.f;
    if (w < WW) v = src[((long)(n * CINF + c0 + cl) * HH + h) * WW + w];
    tile[cl][tx] = v;
  }
  __syncthreads();
  #pragma unroll
  for (int i = 0; i < 4; ++i) {
    int wl = ty + i * 8;
    int w = w0 + wl;
    if (w < WW)
      dst[((long)((n * PH + h + 1) * PW + (w + 1))) * CINF + c0 + tx] = (f16)tile[tx][wl];
  }
}

// ---------------- SE gate ----------------
__global__ void se_gate_kernel(const float* __restrict__ intr,
                               const float* __restrict__ w1, const float* __restrict__ b1,
                               const float* __restrict__ w2, const float* __restrict__ b2,
                               const float* __restrict__ rw, const float* __restrict__ rb,
                               const float* __restrict__ ew, const float* __restrict__ eb,
                               float* __restrict__ gate) {
  __shared__ float sps;
  __shared__ float h1[MIDC];
  __shared__ float h2[MIDC];
  __shared__ float tt[MIDC];
  int n = blockIdx.x, c = threadIdx.x;
  if (c == 0) {
    float a[4][8];
    for (int i = 0; i < 4; ++i)
      for (int j = 0; j < 4; ++j) {
        a[i][j] = intr[n * 16 + i * 4 + j];
        a[i][4 + j] = (i == j) ? 1.f : 0.f;
      }
    for (int col = 0; col < 4; ++col) {
      int piv = col;
      for (int r2 = col + 1; r2 < 4; ++r2)
        if (fabsf(a[r2][col]) > fabsf(a[piv][col])) piv = r2;
      if (piv != col)
        for (int j = 0; j < 8; ++j) { float tv = a[col][j]; a[col][j] = a[piv][j]; a[piv][j] = tv; }
      float invp = 1.f / a[col][col];
      for (int j = 0; j < 8; ++j) a[col][j] *= invp;
      for (int r2 = 0; r2 < 4; ++r2)
        if (r2 != col) {
          float f = a[r2][col];
          for (int j = 0; j < 8; ++j) a[r2][j] -= f * a[col][j];
        }
    }
    float i00 = a[0][4], i11 = a[1][5];
    sps = sqrtf(i00 * i00 + i11 * i11) * 1000.f;
  }
  __syncthreads();
  float sp = sps;
  h1[c] = fmaxf(sp * w1[c] + b1[c], 0.f);
  __syncthreads();
  float acc = b2[c];
  for (int j = 0; j < MIDC; ++j) acc += h1[j] * w2[j * MIDC + c];
  h2[c] = acc;
  __syncthreads();
  acc = rb[c];
  for (int j = 0; j < MIDC; ++j) acc += rw[c * MIDC + j] * h2[j];
  tt[c] = fmaxf(acc, 0.f);
  __syncthreads();
  acc = eb[c];
  for (int j = 0; j < MIDC; ++j) acc += ew[c * MIDC + j] * tt[j];
  gate[n * MIDC + c] = 1.f / (1.f + expf(-acc));
}

// ---------------- MFMA implicit-GEMM conv (r4 champion, unchanged) ----------------
// 128co x 64pos block, 4 waves (2x2), wave 64x32; A+B via global_load_lds into
// 2 x 24KB dbuf; __syncthreads loop (measured == counted-vmcnt, r6); co-interleaved
// bid mapping + XCD swizzle (19MB FETCH floor). Structure floor ~62us/conv0 at
// MfmaUtil ~26%: wave geometry is forced by N*M/CU ~ 16.9K outputs (r7: bigger
// waves -> 1 wave/SIMD -> worse; all sync/latency knobs measured null r3/r5/r6).
// MODE 0: relu(acc+b)*gate   MODE 1: relu(acc+b)   MODE 2: relu(acc+b+res)   MODE 3: acc+b -> f32
template<int MODE, int CIN_T, int TAPS>
__global__ __launch_bounds__(256, 2)
void conv_mfma(const f16* __restrict__ X, const f16* __restrict__ Wf,
               const float* __restrict__ bias, const float* __restrict__ gate,
               const f16* __restrict__ res, f16* __restrict__ Yf16,
               float* __restrict__ Yf32, int co_tiles) {
  constexpr int KST = CIN_T / 32;
  constexpr int CPT = CIN_T / 64;
  constexpr int NCH = TAPS * CPT;
  constexpr int LCPT = (CPT == 8) ? 3 : 2;
  constexpr long GSTR = (long)TAPS * KST * 4096;   // bytes per weight group
  __shared__ __align__(16) char S[49152];          // 2 x (16KB A + 8KB B)

  const int t = threadIdx.x;
  const int wv = t >> 6, ln = t & 63, lm = ln & 15, quad = ln >> 4;
  const int wm = wv >> 1, wn = wv & 1;
  // XCD-aware swizzle: bid0%8 is the XCD; give each XCD a contiguous bid range.
  const int bid0 = blockIdx.x;
  const int cpx = gridDim.x >> 3;                  // grids are %8 == 0
  const int bid = (bid0 & 7) * cpx + (bid0 >> 3);
  const int co_tile = bid % co_tiles;
  const int ptile = bid / co_tiles;
  const int cam = ptile / PT_PER_CAM;
  const int pbase = (ptile % PT_PER_CAM) * PTILE;

  // B DMA setup: 2 instrs/wave, each covers 8 rows x 8 phys chunks
  const f16* gB[2]; int ldsoffB[2];
  const int clog = (ln & 7) ^ (ln >> 3);
  #pragma unroll
  for (int j = 0; j < 2; ++j) {
    int reg = j * 4 + wv;
    int r = reg * 8 + (ln >> 3);
    int pos = pbase + r;
    int hh = pos / WW, w2 = pos - hh * WW;
    gB[j] = X + ((long)((cam * PH + hh + 1) * PW + (w2 + 1))) * CIN_T + clog * 8;
    ldsoffB[j] = 16384 + reg * 1024;
  }

  // lane-constant bf addressing (bytes, within B region)
  const int base_l = (wn * 32 + lm) * 128;
  const int sx0 = ((0 * 4 + quad) ^ (lm & 7)) * 16;
  const int sx1 = ((1 * 4 + quad) ^ (lm & 7)) * 16;

  f32x4 acc[4][2];
  #pragma unroll
  for (int mi = 0; mi < 4; ++mi)
    #pragma unroll
    for (int ni = 0; ni < 2; ++ni)
      #pragma unroll
      for (int r = 0; r < 4; ++r) acc[mi][ni][r] = 0.f;

  auto choff = [&](int c) -> long {
    long off = 0;
    if (TAPS == 9) {
      int tp = c >> LCPT;
      int dy = tp / 3 - 1, dx = tp % 3 - 1;
      off = (long)(dy * PW + dx) * CIN_T;
    }
    return off + (long)(c & (CPT - 1)) * 64;
  };
  // stage one chunk's A (16KB: group0 8KB then group1 8KB) into buffer bsel
  auto stageA = [&](int bsel, int c) {
    const char* sb = (const char*)Wf + (long)c * 8192 + (long)ln * 16;
    char* db = S + bsel * 24576;
    #pragma unroll
    for (int j = 0; j < 4; ++j) {
      int seg = j * 4 + wv;                       // 0..15 (1KB segments)
      long gb = (long)(co_tile * 2 + (seg >> 3)) * GSTR;
      gl_lds16(sb + gb + (seg & 7) * 1024, db + seg * 1024);
    }
  };
  auto stageB = [&](int bsel, long curf) {
    #pragma unroll
    for (int j = 0; j < 2; ++j)
      gl_lds16(gB[j] + curf, S + bsel * 24576 + ldsoffB[j]);
  };
  auto compute = [&](int bsel) {
    const char* ab = S + bsel * 24576 + wm * 8192 + ln * 16;
    const char* bb = S + bsel * 24576 + 16384 + base_l;
    #pragma unroll
    for (int s = 0; s < 2; ++s) {
      f16x8 af[4];
      #pragma unroll
      for (int mi = 0; mi < 4; ++mi)
        af[mi] = *(const f16x8*)(ab + s * 4096 + mi * 1024);
      f16x8 bf[2];
      int sx = s ? sx1 : sx0;
      #pragma unroll
      for (int ni = 0; ni < 2; ++ni)
        bf[ni] = *(const f16x8*)(bb + ni * 2048 + sx);
      #pragma unroll
      for (int mi = 0; mi < 4; ++mi)
        #pragma unroll
        for (int ni = 0; ni < 2; ++ni)
          acc[mi][ni] = __builtin_amdgcn_mfma_f32_16x16x32_f16(af[mi], bf[ni], acc[mi][ni], 0, 0, 0);
    }
  };

  stageA(0, 0);
  stageB(0, choff(0));
  __syncthreads();

  #pragma unroll 1
  for (int c = 0; c < NCH; ++c) {
    int cur = c & 1;
    if (c + 1 < NCH) { stageA(cur ^ 1, c + 1); stageB(cur ^ 1, choff(c + 1)); }
    compute(cur);
    __syncthreads();
  }

  // ---- epilogue: direct stores from acc ----
  float4 b4[4], g4[4];
  bool skip[4];
  #pragma unroll
  for (int mi = 0; mi < 4; ++mi) {
    int co_l = wm * 64 + mi * 16 + quad * 4;
    int co_g = co_tile * 128 + co_l;
    skip[mi] = (MODE == 3) && (co_l >= DB);
    if (!skip[mi]) b4[mi] = *(const float4*)(bias + co_g);
    if (MODE == 0) g4[mi] = *(const float4*)(gate + cam * MIDC + co_g);
  }
  #pragma unroll
  for (int ni = 0; ni < 2; ++ni) {
    int pos = pbase + wn * 32 + ni * 16 + lm;
    long ob;
    if (MODE == 3) ob = ((long)(cam * NPOS + pos)) * DB;
    else {
      int hh = pos / WW, w2 = pos - hh * WW;
      ob = ((long)((cam * PH + hh + 1) * PW + (w2 + 1))) * MIDC + co_tile * 128;
    }
    #pragma unroll
    for (int mi = 0; mi < 4; ++mi) {
      if (skip[mi]) continue;
      int co_l = wm * 64 + mi * 16 + quad * 4;
      float v[4];
      #pragma unroll
      for (int r = 0; r < 4; ++r) {
        float y = acc[mi][ni][r];
        y += ((float*)&b4[mi])[r];
        if (MODE == 0) y = fmaxf(y, 0.f) * ((float*)&g4[mi])[r];
        else if (MODE == 1) y = fmaxf(y, 0.f);
        v[r] = y;
      }
      if (MODE == 3) {
        float4 o; o.x = v[0]; o.y = v[1]; o.z = v[2]; o.w = v[3];
        *(float4*)(Yf32 + ob + co_l) = o;
      } else if (MODE == 2) {
        f16x4 rv = *(const f16x4*)(res + ob + co_l);
        f16x4 o;
        #pragma unroll
        for (int r = 0; r < 4; ++r) o[r] = (f16)fmaxf(v[r] + (float)rv[r], 0.f);
        *(f16x4*)(Yf16 + ob + co_l) = o;
      } else {
        f16x4 o;
        #pragma unroll
        for (int r = 0; r < 4; ++r) o[r] = (f16)v[r];
        *(f16x4*)(Yf16 + ob + co_l) = o;
      }
    }
  }
}

// ---------------- softmax over 112 bins, one wave per position ----------------
__global__ void softmax_kernel(const float* __restrict__ L, float* __restrict__ dp) {
  int wid = (int)(((long)blockIdx.x * blockDim.x + threadIdx.x) >> 6);
  int lane = threadIdx.x & 63;
  if (wid >= NCAM * NPOS) return;
  const float* lp = L + (long)wid * DB;
  float v0 = -1e30f, v1 = -1e30f;
  if (lane < 56) { v0 = lp[lane * 2]; v1 = lp[lane * 2 + 1]; }
  float m = fmaxf(v0, v1);
  #pragma unroll
  for (int o = 32; o; o >>= 1) m = fmaxf(m, __shfl_xor(m, o));
  float e0 = 0.f, e1 = 0.f;
  if (lane < 56) { e0 = __expf(v0 - m); e1 = __expf(v1 - m); }
  float ssum = e0 + e1;
  #pragma unroll
  for (int o = 32; o; o >>= 1) ssum += __shfl_xor(ssum, o);
  float inv = 1.f / ssum;
  if (lane < 56) {
    float2 r; r.x = e0 * inv; r.y = e1 * inv;
    *(float2*)(dp + (long)wid * DB + lane * 2) = r;
  }
}

// ---------------- trilinear grid sample + camera sum + normalize ----------------
__global__ void sample_kernel(const float* __restrict__ grid, const float* __restrict__ dp,
                              float* __restrict__ out) {
  int v = blockIdx.x * blockDim.x + threadIdx.x;
  if (v >= 128 * 128 * 16) return;
  int vz = v & 15, vy = (v >> 4) & 127, vx = v >> 11;
  float agg = 0.f, msk = 0.f;
  #pragma unroll 1
  for (int n = 0; n < NCAM; ++n) {
    long gb = ((long)((n * 128 + vx) * 128 + vy) * 16 + vz) * 3;
    float gx = grid[gb], gy = grid[gb + 1], gz = grid[gb + 2];
    float ix = ((gx + 1.f) * (float)WW - 1.f) * 0.5f;
    float iy = ((gy + 1.f) * (float)HH - 1.f) * 0.5f;
    float iz = ((gz + 1.f) * (float)DB - 1.f) * 0.5f;
    float xf = floorf(ix), yf = floorf(iy), zf = floorf(iz);
    float fx = ix - xf, fy = iy - yf, fz = iz - zf;
    int x0 = (int)xf, y0 = (int)yf, z0 = (int)zf;
    float wxa[2] = {1.f - fx, fx};
    float wya[2] = {1.f - fy, fy};
    float wza[2] = {1.f - fz, fz};
    #pragma unroll
    for (int dy2 = 0; dy2 < 2; ++dy2) {
      int y = y0 + dy2;
      bool vyb = (y >= 0) && (y < HH);
      int yc = y < 0 ? 0 : (y > HH - 1 ? HH - 1 : y);
      #pragma unroll
      for (int dx2 = 0; dx2 < 2; ++dx2) {
        int x = x0 + dx2;
        bool vxb = (x >= 0) && (x < WW);
        int xc = x < 0 ? 0 : (x > WW - 1 ? WW - 1 : x);
        float wxy = wxa[dx2] * wya[dy2];
        const float* base = dp + ((long)((n * HH + yc) * WW + xc)) * DB;
        #pragma unroll
        for (int dz2 = 0; dz2 < 2; ++dz2) {
          int z = z0 + dz2;
          bool vzb = (z >= 0) && (z < DB);
          int zc = z < 0 ? 0 : (z > DB - 1 ? DB - 1 : z);
          float wgt = wxy * wza[dz2];
          if (vxb && vyb && vzb) {
            msk += wgt;
            agg += wgt * base[zc];
          }
        }
      }
    }
  }
  out[v] = (msk > 0.f) ? (agg / msk) : agg;
}

extern "C" void kernel_launch(void* const* d_in, const int* in_sizes, int n_in,
                              void* d_out, int out_size, void* d_ws, size_t ws_size,
                              hipStream_t stream) {
  const float* img   = (const float*)d_in[0];
  const float* intr  = (const float*)d_in[1];
  const float* grid  = (const float*)d_in[2];
  const float* red_w = (const float*)d_in[3];
  const float* red_s = (const float*)d_in[4];
  const float* red_b = (const float*)d_in[5];
  const float* w1    = (const float*)d_in[6];
  const float* b1    = (const float*)d_in[7];
  const float* w2    = (const float*)d_in[8];
  const float* b2    = (const float*)d_in[9];
  const float* rw    = (const float*)d_in[10];
  const float* rb    = (const float*)d_in[11];
  const float* ew    = (const float*)d_in[12];
  const float* eb    = (const float*)d_in[13];
  const float* bb_w  = (const float*)d_in[14];
  const float* bb_s  = (const float*)d_in[15];
  const float* bb_b  = (const float*)d_in[16];
  const float* dp_w  = (const float*)d_in[17];
  const float* dp_b  = (const float*)d_in[18];
  float* out = (float*)d_out;

  char* ws = (char*)d_ws;
  float* gate = (float*)(ws + O_GATE);
  f16* wfred  = (f16*)(ws + O_WFRED);
  f16* wfbb   = (f16*)(ws + O_WFBB);
  f16* wfdp   = (f16*)(ws + O_WFDP);
  f16* xp0    = (f16*)(ws + O_XP0);
  f16* X1     = (f16*)(ws + O_X1);
  f16* X2     = (f16*)(ws + O_X2);
  f16* X3     = (f16*)(ws + O_X3);
  float* Lg   = (float*)(ws + O_LOG);
  float* dpb  = (float*)(ws + O_DP);

  halo_zero_kernel<<<915, 256, 0, stream>>>(xp0, X1, X2, X3);
  // coalesced wfrag: grid = NC * G*32 co-pairs; dynamic LDS = 2*CI*TAPS*4 bytes
  wfrag_kernel<<<128, 256, 36864, stream>>>(red_w, red_s, wfred, 9, 512, 256, 4, 4L * 9 * 16 * 2048);
  wfrag_kernel<<<768, 256, 18432, stream>>>(bb_w, bb_s, wfbb, 9, 256, 256, 4, 4L * 9 * 8 * 2048);
  wfrag_kernel<<<64, 256, 2048, stream>>>(dp_w, nullptr, wfdp, 1, 256, 112, 2, 2L * 1 * 8 * 2048);
  img_trans_kernel<<<dim3(48, 32, 6), 256, 0, stream>>>(img, xp0);
  se_gate_kernel<<<6, 256, 0, stream>>>(intr, w1, b1, w2, b2, rw, rb, ew, eb, gate);

  const long WCH = 4L * 9 * 8 * 2048;  // per-conv fragment-weight stride (f16)

  conv_mfma<0, 512, 9><<<528, 256, 0, stream>>>(xp0, wfred, red_b, gate, nullptr, X1, nullptr, 2);

  conv_mfma<1, 256, 9><<<528, 256, 0, stream>>>(X1, wfbb + 0 * WCH, bb_b + 0 * 256, nullptr, nullptr, X2, nullptr, 2);
  conv_mfma<2, 256, 9><<<528, 256, 0, stream>>>(X2, wfbb + 1 * WCH, bb_b + 1 * 256, nullptr, X1, X3, nullptr, 2);
  conv_mfma<1, 256, 9><<<528, 256, 0, stream>>>(X3, wfbb + 2 * WCH, bb_b + 2 * 256, nullptr, nullptr, X2, nullptr, 2);
  conv_mfma<2, 256, 9><<<528, 256, 0, stream>>>(X2, wfbb + 3 * WCH, bb_b + 3 * 256, nullptr, X3, X1, nullptr, 2);
  conv_mfma<1, 256, 9><<<528, 256, 0, stream>>>(X1, wfbb + 4 * WCH, bb_b + 4 * 256, nullptr, nullptr, X2, nullptr, 2);
  conv_mfma<2, 256, 9><<<528, 256, 0, stream>>>(X2, wfbb + 5 * WCH, bb_b + 5 * 256, nullptr, X1, X3, nullptr, 2);

  conv_mfma<3, 256, 1><<<264, 256, 0, stream>>>(X3, wfdp, dp_b, nullptr, nullptr, nullptr, Lg, 1);

  softmax_kernel<<<4224, 256, 0, stream>>>(Lg, dpb);
  sample_kernel<<<1024, 256, 0, stream>>>(grid, dpb, out);
}

// Round 9
// 462.299 us; speedup vs baseline: 1.1398x; 1.0970x over previous
//
#include <hip/hip_runtime.h>

typedef _Float16 f16;
typedef _Float16 f16x8 __attribute__((ext_vector_type(8)));
typedef _Float16 f16x4 __attribute__((ext_vector_type(4)));
typedef float f32x4 __attribute__((ext_vector_type(4)));

#define NCAM 6
#define CINF 512
#define MIDC 256
#define DB   112
#define HH   32
#define WW   88
#define PH   34
#define PW   90
#define NPOS (HH*WW)       /* 2816 */
#define PTILE 64
#define PT_PER_CAM 44      /* 2816/64 */

// ---- workspace layout (bytes) ----
#define O_GATE   0L
#define O_WFRED  6144L
#define O_WFBB   2365440L
#define O_WFDP   9443328L
#define O_XP0    9508864L
#define O_X1     28309504L
#define O_DP     28309504L    /* overlays X1; written only after X1's last read */
#define O_X2     37709824L
#define O_X3     47110144L
/* end: 56510464 (< 71.6MB known-good ws) */

__device__ __forceinline__ void gl_lds16(const void* g, void* l) {
  __builtin_amdgcn_global_load_lds((const __attribute__((address_space(1))) void*)g,
                                   (__attribute__((address_space(3))) void*)l, 16, 0, 0);
}

// ---------------- fused preprocessing: halo zero + img transpose + SE gate + wfrag x3 ----
// All six sub-kernels are mutually independent (disjoint outputs; halo writes pad cells,
// img_trans writes interior cells). One launch removes 5 launch gaps from the serial
// stream. Block ranges:
//   [0,915)            halo_zero           (xp0, X1, X2, X3 halos)
//   [915,10131)        img_trans           (9216 virtual blocks, 48x32x6)
//   [10131,10137)      se_gate             (6 blocks)
//   [10137,12185)      wfrag red           (2048-block grid-stride)
//   [12185,16281)      wfrag bb            (4096-block grid-stride)
//   [16281,16409)      wfrag dp            (128-block grid-stride)
__device__ void wfrag_body(const float* __restrict__ src, const float* __restrict__ scale,
                           f16* __restrict__ dst, int TAPS, int CI, int CO_SRC,
                           long per, long total, int lbid, int nb) {
  long i = (long)lbid * 256 + threadIdx.x;
  long stride = (long)nb * 256;
  int KST = CI >> 5;
  for (; i < total; i += stride) {
    int conv = (int)(i / per);
    long rem = i - (long)conv * per;
    int j = (int)(rem & 7);
    int lane = (int)((rem >> 3) & 63);
    int mi = (int)((rem >> 9) & 3);
    long b = rem >> 11;
    int ks = (int)(b % KST);
    long b2 = b / KST;
    int tap = (int)(b2 % TAPS);
    int g = (int)(b2 / TAPS);
    int co = g * 64 + mi * 16 + (lane & 15);
    int ci = ks * 32 + (lane >> 4) * 8 + j;
    float v = 0.f;
    if (co < CO_SRC) {
      v = src[(long)conv * CO_SRC * CI * TAPS + ((long)co * CI + ci) * TAPS + tap];
      if (scale) v *= scale[conv * CO_SRC + co];
    }
    dst[i] = (f16)v;
  }
}

__global__ void prep_kernel(f16* __restrict__ xp0, f16* __restrict__ X1,
                            f16* __restrict__ X2, f16* __restrict__ X3,
                            const float* __restrict__ img,
                            const float* __restrict__ intr,
                            const float* __restrict__ w1, const float* __restrict__ b1,
                            const float* __restrict__ w2, const float* __restrict__ b2,
                            const float* __restrict__ rw, const float* __restrict__ rb,
                            const float* __restrict__ ew, const float* __restrict__ eb,
                            float* __restrict__ gate,
                            const float* __restrict__ red_w, const float* __restrict__ red_s,
                            f16* __restrict__ wfred,
                            const float* __restrict__ bb_w, const float* __restrict__ bb_s,
                            f16* __restrict__ wfbb,
                            const float* __restrict__ dp_w, f16* __restrict__ wfdp) {
  __shared__ float shbuf[1056];
  const int bid = blockIdx.x;
  if (bid < 915) {
    // ---- halo zero ----
    int idx = bid * 256 + threadIdx.x;
    f16* base; int C, rem;
    if (idx < 93696) { base = xp0; C = 512; rem = idx; }
    else {
      int k = idx - 93696;
      int bsel = k / 46848;
      if (bsel >= 3) return;
      rem = k - bsel * 46848; C = 256;
      base = (bsel == 0) ? X1 : (bsel == 1) ? X2 : X3;
    }
    int chunks = C >> 3;
    int cell = rem / chunks, cc = rem - cell * chunks;
    int cam = cell / 244, p = cell - cam * 244;
    int hh, ww;
    if (p < 90)       { hh = 0;  ww = p; }
    else if (p < 180) { hh = 33; ww = p - 90; }
    else { int q = p - 180; hh = 1 + (q >> 1); ww = (q & 1) * 89; }
    long o = ((long)(cam * PH + hh) * PW + ww) * C + cc * 8;
    f16x8 z = {0,0,0,0,0,0,0,0};
    *(f16x8*)(base + o) = z;
  } else if (bid < 10131) {
    // ---- img NCHW f32 -> padded NHWC f16 ----
    int lb = bid - 915;
    int x = lb % 48;
    int h = (lb / 48) % 32;
    int n = lb / 1536;
    int wt = x % 3, ct = x / 3;
    float (*tile)[33] = (float(*)[33])shbuf;
    int tx = threadIdx.x & 31, ty = threadIdx.x >> 5;
    int w0 = wt * 32, c0 = ct * 32;
    #pragma unroll
    for (int i = 0; i < 4; ++i) {
      int cl = ty + i * 8;
      int w = w0 + tx;
      float v = 0.f;
      if (w < WW) v = img[((long)(n * CINF + c0 + cl) * HH + h) * WW + w];
      tile[cl][tx] = v;
    }
    __syncthreads();
    #pragma unroll
    for (int i = 0; i < 4; ++i) {
      int wl = ty + i * 8;
      int w = w0 + wl;
      if (w < WW)
        xp0[((long)((n * PH + h + 1) * PW + (w + 1))) * CINF + c0 + tx] = (f16)tile[tx][wl];
    }
  } else if (bid < 10137) {
    // ---- SE gate ----
    int n = bid - 10131, c = threadIdx.x;
    float* sps = shbuf;
    float* h1 = shbuf + 32;
    float* h2 = shbuf + 288;
    float* tt = shbuf + 544;
    if (c == 0) {
      float a[4][8];
      for (int i = 0; i < 4; ++i)
        for (int j = 0; j < 4; ++j) {
          a[i][j] = intr[n * 16 + i * 4 + j];
          a[i][4 + j] = (i == j) ? 1.f : 0.f;
        }
      for (int col = 0; col < 4; ++col) {
        int piv = col;
        for (int r2 = col + 1; r2 < 4; ++r2)
          if (fabsf(a[r2][col]) > fabsf(a[piv][col])) piv = r2;
        if (piv != col)
          for (int j = 0; j < 8; ++j) { float tv = a[col][j]; a[col][j] = a[piv][j]; a[piv][j] = tv; }
        float invp = 1.f / a[col][col];
        for (int j = 0; j < 8; ++j) a[col][j] *= invp;
        for (int r2 = 0; r2 < 4; ++r2)
          if (r2 != col) {
            float f = a[r2][col];
            for (int j = 0; j < 8; ++j) a[r2][j] -= f * a[col][j];
          }
      }
      float i00 = a[0][4], i11 = a[1][5];
      sps[0] = sqrtf(i00 * i00 + i11 * i11) * 1000.f;
    }
    __syncthreads();
    float sp = sps[0];
    h1[c] = fmaxf(sp * w1[c] + b1[c], 0.f);
    __syncthreads();
    float acc = b2[c];
    for (int j = 0; j < MIDC; ++j) acc += h1[j] * w2[j * MIDC + c];
    h2[c] = acc;
    __syncthreads();
    acc = rb[c];
    for (int j = 0; j < MIDC; ++j) acc += rw[c * MIDC + j] * h2[j];
    tt[c] = fmaxf(acc, 0.f);
    __syncthreads();
    acc = eb[c];
    for (int j = 0; j < MIDC; ++j) acc += ew[c * MIDC + j] * tt[j];
    gate[n * MIDC + c] = 1.f / (1.f + expf(-acc));
  } else if (bid < 12185) {
    long per = 4L * 9 * 16 * 2048;
    wfrag_body(red_w, red_s, wfred, 9, 512, 256, per, per, bid - 10137, 2048);
  } else if (bid < 16281) {
    long per = 4L * 9 * 8 * 2048;
    wfrag_body(bb_w, bb_s, wfbb, 9, 256, 256, per, 6 * per, bid - 12185, 4096);
  } else {
    long per = 2L * 1 * 8 * 2048;
    wfrag_body(dp_w, nullptr, wfdp, 1, 256, 112, per, per, bid - 16281, 128);
  }
}

// ---------------- MFMA implicit-GEMM conv (r4 champion structure) ----------------
// 128co x 64pos block, 4 waves (2x2), wave 64x32; A+B via global_load_lds into
// 2 x 24KB dbuf; __syncthreads loop (measured == counted-vmcnt, r6); co-interleaved
// bid mapping + XCD swizzle (19MB FETCH floor). Structure floor ~62us/conv0 at
// MfmaUtil ~26% (LDS pipe ~73% busy: 96KB ds_read + 48KB DMA-write per CU-chunk).
// MODE 3 now fuses the depth softmax into the epilogue: the block (co_tiles=1) holds
// all 112 bins for its 64 positions -> stage acc+bias to LDS [64][116], 4 threads per
// position reduce via shfl_xor(1,2), write normalized dp directly (removes the
// softmax kernel and the 15MB logits round-trip).
// MODE 0: relu(acc+b)*gate   MODE 1: relu(acc+b)   MODE 2: relu(acc+b+res)   MODE 3: softmax->f32
template<int MODE, int CIN_T, int TAPS>
__global__ __launch_bounds__(256, 2)
void conv_mfma(const f16* __restrict__ X, const f16* __restrict__ Wf,
               const float* __restrict__ bias, const float* __restrict__ gate,
               const f16* __restrict__ res, f16* __restrict__ Yf16,
               float* __restrict__ Yf32, int co_tiles) {
  constexpr int KST = CIN_T / 32;
  constexpr int CPT = CIN_T / 64;
  constexpr int NCH = TAPS * CPT;
  constexpr int LCPT = (CPT == 8) ? 3 : 2;
  constexpr long GSTR = (long)TAPS * KST * 4096;   // bytes per weight group
  __shared__ __align__(16) char S[49152];          // 2 x (16KB A + 8KB B)

  const int t = threadIdx.x;
  const int wv = t >> 6, ln = t & 63, lm = ln & 15, quad = ln >> 4;
  const int wm = wv >> 1, wn = wv & 1;
  // XCD-aware swizzle: bid0%8 is the XCD; give each XCD a contiguous bid range.
  const int bid0 = blockIdx.x;
  const int cpx = gridDim.x >> 3;                  // grids are %8 == 0
  const int bid = (bid0 & 7) * cpx + (bid0 >> 3);
  const int co_tile = bid % co_tiles;
  const int ptile = bid / co_tiles;
  const int cam = ptile / PT_PER_CAM;
  const int pbase = (ptile % PT_PER_CAM) * PTILE;

  // B DMA setup: 2 instrs/wave, each covers 8 rows x 8 phys chunks
  const f16* gB[2]; int ldsoffB[2];
  const int clog = (ln & 7) ^ (ln >> 3);
  #pragma unroll
  for (int j = 0; j < 2; ++j) {
    int reg = j * 4 + wv;
    int r = reg * 8 + (ln >> 3);
    int pos = pbase + r;
    int hh = pos / WW, w2 = pos - hh * WW;
    gB[j] = X + ((long)((cam * PH + hh + 1) * PW + (w2 + 1))) * CIN_T + clog * 8;
    ldsoffB[j] = 16384 + reg * 1024;
  }

  // lane-constant bf addressing (bytes, within B region)
  const int base_l = (wn * 32 + lm) * 128;
  const int sx0 = ((0 * 4 + quad) ^ (lm & 7)) * 16;
  const int sx1 = ((1 * 4 + quad) ^ (lm & 7)) * 16;

  f32x4 acc[4][2];
  #pragma unroll
  for (int mi = 0; mi < 4; ++mi)
    #pragma unroll
    for (int ni = 0; ni < 2; ++ni)
      #pragma unroll
      for (int r = 0; r < 4; ++r) acc[mi][ni][r] = 0.f;

  auto choff = [&](int c) -> long {
    long off = 0;
    if (TAPS == 9) {
      int tp = c >> LCPT;
      int dy = tp / 3 - 1, dx = tp % 3 - 1;
      off = (long)(dy * PW + dx) * CIN_T;
    }
    return off + (long)(c & (CPT - 1)) * 64;
  };
  // stage one chunk's A (16KB: group0 8KB then group1 8KB) into buffer bsel
  auto stageA = [&](int bsel, int c) {
    const char* sb = (const char*)Wf + (long)c * 8192 + (long)ln * 16;
    char* db = S + bsel * 24576;
    #pragma unroll
    for (int j = 0; j < 4; ++j) {
      int seg = j * 4 + wv;                       // 0..15 (1KB segments)
      long gb = (long)(co_tile * 2 + (seg >> 3)) * GSTR;
      gl_lds16(sb + gb + (seg & 7) * 1024, db + seg * 1024);
    }
  };
  auto stageB = [&](int bsel, long curf) {
    #pragma unroll
    for (int j = 0; j < 2; ++j)
      gl_lds16(gB[j] + curf, S + bsel * 24576 + ldsoffB[j]);
  };
  auto compute = [&](int bsel) {
    const char* ab = S + bsel * 24576 + wm * 8192 + ln * 16;
    const char* bb = S + bsel * 24576 + 16384 + base_l;
    #pragma unroll
    for (int s = 0; s < 2; ++s) {
      f16x8 af[4];
      #pragma unroll
      for (int mi = 0; mi < 4; ++mi)
        af[mi] = *(const f16x8*)(ab + s * 4096 + mi * 1024);
      f16x8 bf[2];
      int sx = s ? sx1 : sx0;
      #pragma unroll
      for (int ni = 0; ni < 2; ++ni)
        bf[ni] = *(const f16x8*)(bb + ni * 2048 + sx);
      #pragma unroll
      for (int mi = 0; mi < 4; ++mi)
        #pragma unroll
        for (int ni = 0; ni < 2; ++ni)
          acc[mi][ni] = __builtin_amdgcn_mfma_f32_16x16x32_f16(af[mi], bf[ni], acc[mi][ni], 0, 0, 0);
    }
  };

  stageA(0, 0);
  stageB(0, choff(0));
  __syncthreads();

  #pragma unroll 1
  for (int c = 0; c < NCH; ++c) {
    int cur = c & 1;
    if (c + 1 < NCH) { stageA(cur ^ 1, c + 1); stageB(cur ^ 1, choff(c + 1)); }
    compute(cur);
    __syncthreads();
  }

  // ---- epilogue ----
  float4 b4[4], g4[4];
  bool skip[4];
  #pragma unroll
  for (int mi = 0; mi < 4; ++mi) {
    int co_l = wm * 64 + mi * 16 + quad * 4;
    int co_g = co_tile * 128 + co_l;
    skip[mi] = (MODE == 3) && (co_l >= DB);
    if (!skip[mi]) b4[mi] = *(const float4*)(bias + co_g);
    if (MODE == 0) g4[mi] = *(const float4*)(gate + cam * MIDC + co_g);
  }

  if (MODE == 3) {
    // fused depth softmax: stage logits to LDS [64 pos][116 bins], reduce 4 thr/pos.
    // (K-loop's final __syncthreads fences all LDS reads; S is reusable here.)
    float* P = (float*)S;
    #pragma unroll
    for (int ni = 0; ni < 2; ++ni) {
      int prow = wn * 32 + ni * 16 + lm;
      #pragma unroll
      for (int mi = 0; mi < 4; ++mi) {
        if (skip[mi]) continue;
        int co_l = wm * 64 + mi * 16 + quad * 4;
        float4 o;
        o.x = acc[mi][ni][0] + ((float*)&b4[mi])[0];
        o.y = acc[mi][ni][1] + ((float*)&b4[mi])[1];
        o.z = acc[mi][ni][2] + ((float*)&b4[mi])[2];
        o.w = acc[mi][ni][3] + ((float*)&b4[mi])[3];
        *(float4*)(P + prow * 116 + co_l) = o;
      }
    }
    __syncthreads();
    int p = t >> 2, k = t & 3;
    const float* Pr = P + p * 116;
    float m = -1e30f;
    for (int b = k; b < DB; b += 4) m = fmaxf(m, Pr[b]);
    m = fmaxf(m, __shfl_xor(m, 1));
    m = fmaxf(m, __shfl_xor(m, 2));
    float e[28];
    float ssum = 0.f;
    int cnt = 0;
    for (int b = k; b < DB; b += 4) { float ev = __expf(Pr[b] - m); e[cnt++] = ev; ssum += ev; }
    ssum += __shfl_xor(ssum, 1);
    ssum += __shfl_xor(ssum, 2);
    float inv = 1.f / ssum;
    float* op = Yf32 + ((long)(cam * NPOS + pbase + p)) * DB;
    cnt = 0;
    for (int b = k; b < DB; b += 4) op[b] = e[cnt++] * inv;
    return;
  }

  #pragma unroll
  for (int ni = 0; ni < 2; ++ni) {
    int pos = pbase + wn * 32 + ni * 16 + lm;
    int hh = pos / WW, w2 = pos - hh * WW;
    long ob = ((long)((cam * PH + hh + 1) * PW + (w2 + 1))) * MIDC + co_tile * 128;
    #pragma unroll
    for (int mi = 0; mi < 4; ++mi) {
      int co_l = wm * 64 + mi * 16 + quad * 4;
      float v[4];
      #pragma unroll
      for (int r = 0; r < 4; ++r) {
        float y = acc[mi][ni][r];
        y += ((float*)&b4[mi])[r];
        if (MODE == 0) y = fmaxf(y, 0.f) * ((float*)&g4[mi])[r];
        else if (MODE == 1) y = fmaxf(y, 0.f);
        v[r] = y;
      }
      if (MODE == 2) {
        f16x4 rv = *(const f16x4*)(res + ob + co_l);
        f16x4 o;
        #pragma unroll
        for (int r = 0; r < 4; ++r) o[r] = (f16)fmaxf(v[r] + (float)rv[r], 0.f);
        *(f16x4*)(Yf16 + ob + co_l) = o;
      } else {
        f16x4 o;
        #pragma unroll
        for (int r = 0; r < 4; ++r) o[r] = (f16)v[r];
        *(f16x4*)(Yf16 + ob + co_l) = o;
      }
    }
  }
}

// ---------------- trilinear grid sample + camera sum + normalize ----------------
__global__ void sample_kernel(const float* __restrict__ grid, const float* __restrict__ dp,
                              float* __restrict__ out) {
  int v = blockIdx.x * blockDim.x + threadIdx.x;
  if (v >= 128 * 128 * 16) return;
  int vz = v & 15, vy = (v >> 4) & 127, vx = v >> 11;
  float agg = 0.f, msk = 0.f;
  #pragma unroll 1
  for (int n = 0; n < NCAM; ++n) {
    long gb = ((long)((n * 128 + vx) * 128 + vy) * 16 + vz) * 3;
    float gx = grid[gb], gy = grid[gb + 1], gz = grid[gb + 2];
    float ix = ((gx + 1.f) * (float)WW - 1.f) * 0.5f;
    float iy = ((gy + 1.f) * (float)HH - 1.f) * 0.5f;
    float iz = ((gz + 1.f) * (float)DB - 1.f) * 0.5f;
    float xf = floorf(ix), yf = floorf(iy), zf = floorf(iz);
    float fx = ix - xf, fy = iy - yf, fz = iz - zf;
    int x0 = (int)xf, y0 = (int)yf, z0 = (int)zf;
    float wxa[2] = {1.f - fx, fx};
    float wya[2] = {1.f - fy, fy};
    float wza[2] = {1.f - fz, fz};
    #pragma unroll
    for (int dy2 = 0; dy2 < 2; ++dy2) {
      int y = y0 + dy2;
      bool vyb = (y >= 0) && (y < HH);
      int yc = y < 0 ? 0 : (y > HH - 1 ? HH - 1 : y);
      #pragma unroll
      for (int dx2 = 0; dx2 < 2; ++dx2) {
        int x = x0 + dx2;
        bool vxb = (x >= 0) && (x < WW);
        int xc = x < 0 ? 0 : (x > WW - 1 ? WW - 1 : x);
        float wxy = wxa[dx2] * wya[dy2];
        const float* base = dp + ((long)((n * HH + yc) * WW + xc)) * DB;
        #pragma unroll
        for (int dz2 = 0; dz2 < 2; ++dz2) {
          int z = z0 + dz2;
          bool vzb = (z >= 0) && (z < DB);
          int zc = z < 0 ? 0 : (z > DB - 1 ? DB - 1 : z);
          float wgt = wxy * wza[dz2];
          if (vxb && vyb && vzb) {
            msk += wgt;
            agg += wgt * base[zc];
          }
        }
      }
    }
  }
  out[v] = (msk > 0.f) ? (agg / msk) : agg;
}

extern "C" void kernel_launch(void* const* d_in, const int* in_sizes, int n_in,
                              void* d_out, int out_size, void* d_ws, size_t ws_size,
                              hipStream_t stream) {
  const float* img   = (const float*)d_in[0];
  const float* intr  = (const float*)d_in[1];
  const float* grid  = (const float*)d_in[2];
  const float* red_w = (const float*)d_in[3];
  const float* red_s = (const float*)d_in[4];
  const float* red_b = (const float*)d_in[5];
  const float* w1    = (const float*)d_in[6];
  const float* b1    = (const float*)d_in[7];
  const float* w2    = (const float*)d_in[8];
  const float* b2    = (const float*)d_in[9];
  const float* rw    = (const float*)d_in[10];
  const float* rb    = (const float*)d_in[11];
  const float* ew    = (const float*)d_in[12];
  const float* eb    = (const float*)d_in[13];
  const float* bb_w  = (const float*)d_in[14];
  const float* bb_s  = (const float*)d_in[15];
  const float* bb_b  = (const float*)d_in[16];
  const float* dp_w  = (const float*)d_in[17];
  const float* dp_b  = (const float*)d_in[18];
  float* out = (float*)d_out;

  char* ws = (char*)d_ws;
  float* gate = (float*)(ws + O_GATE);
  f16* wfred  = (f16*)(ws + O_WFRED);
  f16* wfbb   = (f16*)(ws + O_WFBB);
  f16* wfdp   = (f16*)(ws + O_WFDP);
  f16* xp0    = (f16*)(ws + O_XP0);
  f16* X1     = (f16*)(ws + O_X1);
  f16* X2     = (f16*)(ws + O_X2);
  f16* X3     = (f16*)(ws + O_X3);
  float* dpb  = (float*)(ws + O_DP);

  prep_kernel<<<16409, 256, 0, stream>>>(xp0, X1, X2, X3, img,
                                         intr, w1, b1, w2, b2, rw, rb, ew, eb, gate,
                                         red_w, red_s, wfred, bb_w, bb_s, wfbb, dp_w, wfdp);

  const long WCH = 4L * 9 * 8 * 2048;  // per-conv fragment-weight stride (f16)

  conv_mfma<0, 512, 9><<<528, 256, 0, stream>>>(xp0, wfred, red_b, gate, nullptr, X1, nullptr, 2);

  conv_mfma<1, 256, 9><<<528, 256, 0, stream>>>(X1, wfbb + 0 * WCH, bb_b + 0 * 256, nullptr, nullptr, X2, nullptr, 2);
  conv_mfma<2, 256, 9><<<528, 256, 0, stream>>>(X2, wfbb + 1 * WCH, bb_b + 1 * 256, nullptr, X1, X3, nullptr, 2);
  conv_mfma<1, 256, 9><<<528, 256, 0, stream>>>(X3, wfbb + 2 * WCH, bb_b + 2 * 256, nullptr, nullptr, X2, nullptr, 2);
  conv_mfma<2, 256, 9><<<528, 256, 0, stream>>>(X2, wfbb + 3 * WCH, bb_b + 3 * 256, nullptr, X3, X1, nullptr, 2);
  conv_mfma<1, 256, 9><<<528, 256, 0, stream>>>(X1, wfbb + 4 * WCH, bb_b + 4 * 256, nullptr, nullptr, X2, nullptr, 2);
  conv_mfma<2, 256, 9><<<528, 256, 0, stream>>>(X2, wfbb + 5 * WCH, bb_b + 5 * 256, nullptr, X1, X3, nullptr, 2);

  // dp conv with fused softmax -> writes normalized dp directly
  conv_mfma<3, 256, 1><<<264, 256, 0, stream>>>(X3, wfdp, dp_b, nullptr, nullptr, nullptr, dpb, 1);

  sample_kernel<<<1024, 256, 0, stream>>>(grid, dpb, out);
}

// Round 10
// 459.573 us; speedup vs baseline: 1.1466x; 1.0059x over previous
//
#include <hip/hip_runtime.h>

typedef _Float16 f16;
typedef _Float16 f16x8 __attribute__((ext_vector_type(8)));
typedef _Float16 f16x4 __attribute__((ext_vector_type(4)));
typedef float f32x4 __attribute__((ext_vector_type(4)));

#define NCAM 6
#define CINF 512
#define MIDC 256
#define DB   112
#define HH   32
#define WW   88
#define PH   34
#define PW   90
#define NPOS (HH*WW)       /* 2816 */
#define PTILE 64
#define PT_PER_CAM 44      /* 2816/64 */

// ---- workspace layout (bytes) ----
#define O_GATE   0L
#define O_WFRED  6144L
#define O_WFBB   2365440L
#define O_WFDP   9443328L
#define O_XP0    9508864L
#define O_X1     28309504L
#define O_DP     28309504L    /* overlays X1; written only after X1's last read */
#define O_X2     37709824L
#define O_X3     47110144L
/* end: 56510464 (< 71.6MB known-good ws) */

__device__ __forceinline__ void gl_lds16(const void* g, void* l) {
  __builtin_amdgcn_global_load_lds((const __attribute__((address_space(1))) void*)g,
                                   (__attribute__((address_space(3))) void*)l, 16, 0, 0);
}

// ---------------- coalesced wfrag: one block per (conv, co-pair) ----------------
// r8-verified. Phase 1: read the pair's contiguous 2*CI*TAPS f32 span coalesced into
// LDS. Phase 2: emit 16B fragment-order chunks. Removes the 36B-lane-stride src read
// (~9x cache-line amplification) of the naive per-element version.
// dst idx = (((g*TAPS+tap)*KST+ks)<<11) + (mi<<9) + (lane<<3) + j,
// co = g*64+mi*16+(lane&15), ci = ks*32+(lane>>4)*8+j, scale folded.
__device__ void wfrag_pair(const float* __restrict__ src, const float* __restrict__ scale,
                           f16* __restrict__ dst, int TAPS, int CI, int CO_SRC, int G,
                           long dstride, int lbid, float* __restrict__ W) {
  const int pairs = G * 32;
  const int pair = lbid % pairs;
  const int conv = lbid / pairs;
  const int co0 = pair * 2;
  const int span1 = CI * TAPS;
  const int span = 2 * span1;
  const float* s0 = src + ((long)conv * CO_SRC + co0) * span1;
  for (int i = threadIdx.x; i < span; i += 256) {
    int co_rel = i / span1;
    float v = 0.f;
    if (co0 + co_rel < CO_SRC) v = s0[i];
    W[i] = v;
  }
  __syncthreads();
  const int KST = CI >> 5;
  const int nchunk = 2 * TAPS * KST * 4;
  float sc[2];
  sc[0] = (scale && co0 < CO_SRC) ? scale[conv * CO_SRC + co0] : 1.f;
  sc[1] = (scale && co0 + 1 < CO_SRC) ? scale[conv * CO_SRC + co0 + 1] : 1.f;
  f16* db = dst + (long)conv * dstride;
  for (int cnk = threadIdx.x; cnk < nchunk; cnk += 256) {
    int quad = cnk & 3;
    int b = cnk >> 2;
    int ks = b % KST;
    int b2 = b / KST;
    int tap = b2 % TAPS;
    int cosel = b2 / TAPS;
    int co = co0 + cosel;
    int g = co >> 6, mi = (co >> 4) & 3, lm = co & 15;
    f16 tmp[8];
    #pragma unroll
    for (int j = 0; j < 8; ++j) {
      int ci = ks * 32 + quad * 8 + j;
      tmp[j] = (f16)(W[cosel * span1 + ci * TAPS + tap] * sc[cosel]);
    }
    long o = ((long)((g * TAPS + tap) * KST + ks) << 11) + (mi << 9) + ((quad * 16 + lm) << 3);
    *(f16x8*)(db + o) = *(const f16x8*)tmp;
  }
}

// ---------------- fused preprocessing: halo + img transpose + SE gate + wfrag x3 ----
// All sub-kernels mutually independent (disjoint outputs). Block ranges:
//   [0,915)            halo_zero
//   [915,10131)        img_trans   (9216 virtual blocks, 48x32x6)
//   [10131,10137)      se_gate     (6 blocks)
//   [10137,10265)      wfrag red   (128 co-pair blocks)
//   [10265,11033)      wfrag bb    (768 = 6 convs x 128)
//   [11033,11097)      wfrag dp    (64)
__global__ void prep_kernel(f16* __restrict__ xp0, f16* __restrict__ X1,
                            f16* __restrict__ X2, f16* __restrict__ X3,
                            const float* __restrict__ img,
                            const float* __restrict__ intr,
                            const float* __restrict__ w1, const float* __restrict__ b1,
                            const float* __restrict__ w2, const float* __restrict__ b2,
                            const float* __restrict__ rw, const float* __restrict__ rb,
                            const float* __restrict__ ew, const float* __restrict__ eb,
                            float* __restrict__ gate,
                            const float* __restrict__ red_w, const float* __restrict__ red_s,
                            f16* __restrict__ wfred,
                            const float* __restrict__ bb_w, const float* __restrict__ bb_s,
                            f16* __restrict__ wfbb,
                            const float* __restrict__ dp_w, f16* __restrict__ wfdp) {
  __shared__ __align__(16) float shf[9216];       // 36864 B (wfrag red span; others alias)
  const int bid = blockIdx.x;
  if (bid < 915) {
    // ---- halo zero ----
    int idx = bid * 256 + threadIdx.x;
    f16* base; int C, rem;
    if (idx < 93696) { base = xp0; C = 512; rem = idx; }
    else {
      int k = idx - 93696;
      int bsel = k / 46848;
      if (bsel >= 3) return;
      rem = k - bsel * 46848; C = 256;
      base = (bsel == 0) ? X1 : (bsel == 1) ? X2 : X3;
    }
    int chunks = C >> 3;
    int cell = rem / chunks, cc = rem - cell * chunks;
    int cam = cell / 244, p = cell - cam * 244;
    int hh, ww;
    if (p < 90)       { hh = 0;  ww = p; }
    else if (p < 180) { hh = 33; ww = p - 90; }
    else { int q = p - 180; hh = 1 + (q >> 1); ww = (q & 1) * 89; }
    long o = ((long)(cam * PH + hh) * PW + ww) * C + cc * 8;
    f16x8 z = {0,0,0,0,0,0,0,0};
    *(f16x8*)(base + o) = z;
  } else if (bid < 10131) {
    // ---- img NCHW f32 -> padded NHWC f16 ----
    int lb = bid - 915;
    int x = lb % 48;
    int h = (lb / 48) % 32;
    int n = lb / 1536;
    int wt = x % 3, ct = x / 3;
    float (*tile)[33] = (float(*)[33])shf;
    int tx = threadIdx.x & 31, ty = threadIdx.x >> 5;
    int w0 = wt * 32, c0 = ct * 32;
    #pragma unroll
    for (int i = 0; i < 4; ++i) {
      int cl = ty + i * 8;
      int w = w0 + tx;
      float v = 0.f;
      if (w < WW) v = img[((long)(n * CINF + c0 + cl) * HH + h) * WW + w];
      tile[cl][tx] = v;
    }
    __syncthreads();
    #pragma unroll
    for (int i = 0; i < 4; ++i) {
      int wl = ty + i * 8;
      int w = w0 + wl;
      if (w < WW)
        xp0[((long)((n * PH + h + 1) * PW + (w + 1))) * CINF + c0 + tx] = (f16)tile[tx][wl];
    }
  } else if (bid < 10137) {
    // ---- SE gate ----
    int n = bid - 10131, c = threadIdx.x;
    float* sps = shf;
    float* h1 = shf + 32;
    float* h2 = shf + 288;
    float* tt = shf + 544;
    if (c == 0) {
      float a[4][8];
      for (int i = 0; i < 4; ++i)
        for (int j = 0; j < 4; ++j) {
          a[i][j] = intr[n * 16 + i * 4 + j];
          a[i][4 + j] = (i == j) ? 1.f : 0.f;
        }
      for (int col = 0; col < 4; ++col) {
        int piv = col;
        for (int r2 = col + 1; r2 < 4; ++r2)
          if (fabsf(a[r2][col]) > fabsf(a[piv][col])) piv = r2;
        if (piv != col)
          for (int j = 0; j < 8; ++j) { float tv = a[col][j]; a[col][j] = a[piv][j]; a[piv][j] = tv; }
        float invp = 1.f / a[col][col];
        for (int j = 0; j < 8; ++j) a[col][j] *= invp;
        for (int r2 = 0; r2 < 4; ++r2)
          if (r2 != col) {
            float f = a[r2][col];
            for (int j = 0; j < 8; ++j) a[r2][j] -= f * a[col][j];
          }
      }
      float i00 = a[0][4], i11 = a[1][5];
      sps[0] = sqrtf(i00 * i00 + i11 * i11) * 1000.f;
    }
    __syncthreads();
    float sp = sps[0];
    h1[c] = fmaxf(sp * w1[c] + b1[c], 0.f);
    __syncthreads();
    float acc = b2[c];
    for (int j = 0; j < MIDC; ++j) acc += h1[j] * w2[j * MIDC + c];
    h2[c] = acc;
    __syncthreads();
    acc = rb[c];
    for (int j = 0; j < MIDC; ++j) acc += rw[c * MIDC + j] * h2[j];
    tt[c] = fmaxf(acc, 0.f);
    __syncthreads();
    acc = eb[c];
    for (int j = 0; j < MIDC; ++j) acc += ew[c * MIDC + j] * tt[j];
    gate[n * MIDC + c] = 1.f / (1.f + expf(-acc));
  } else if (bid < 10265) {
    wfrag_pair(red_w, red_s, wfred, 9, 512, 256, 4, 4L * 9 * 16 * 2048, bid - 10137, shf);
  } else if (bid < 11033) {
    wfrag_pair(bb_w, bb_s, wfbb, 9, 256, 256, 4, 4L * 9 * 8 * 2048, bid - 10265, shf);
  } else {
    wfrag_pair(dp_w, nullptr, wfdp, 1, 256, 112, 2, 2L * 1 * 8 * 2048, bid - 11033, shf);
  }
}

// ---------------- MFMA implicit-GEMM conv (r4 champion structure) ----------------
// 128co x 64pos block, 4 waves (2x2), wave 64x32; A+B via global_load_lds into
// 2 x 24KB dbuf; __syncthreads loop (measured == counted-vmcnt, r6); co-interleaved
// bid mapping + XCD swizzle (19MB FETCH floor). Structure floor ~62us/conv0 at
// MfmaUtil ~26% (LDS pipe ~60-75% busy + 2-wave/SIMD dependency stalls; r0-r7:
// occupancy/fetch/pipeline/tile-geometry knobs all null or negative).
// MODE 3 fuses the depth softmax into the epilogue (dp written normalized, no logits
// round-trip). MODE 0: relu(acc+b)*gate  1: relu(acc+b)  2: relu(acc+b+res)  3: softmax->f32
template<int MODE, int CIN_T, int TAPS>
__global__ __launch_bounds__(256, 2)
void conv_mfma(const f16* __restrict__ X, const f16* __restrict__ Wf,
               const float* __restrict__ bias, const float* __restrict__ gate,
               const f16* __restrict__ res, f16* __restrict__ Yf16,
               float* __restrict__ Yf32, int co_tiles) {
  constexpr int KST = CIN_T / 32;
  constexpr int CPT = CIN_T / 64;
  constexpr int NCH = TAPS * CPT;
  constexpr int LCPT = (CPT == 8) ? 3 : 2;
  constexpr long GSTR = (long)TAPS * KST * 4096;   // bytes per weight group
  __shared__ __align__(16) char S[49152];          // 2 x (16KB A + 8KB B)

  const int t = threadIdx.x;
  const int wv = t >> 6, ln = t & 63, lm = ln & 15, quad = ln >> 4;
  const int wm = wv >> 1, wn = wv & 1;
  // XCD-aware swizzle: bid0%8 is the XCD; give each XCD a contiguous bid range.
  const int bid0 = blockIdx.x;
  const int cpx = gridDim.x >> 3;                  // grids are %8 == 0
  const int bid = (bid0 & 7) * cpx + (bid0 >> 3);
  const int co_tile = bid % co_tiles;
  const int ptile = bid / co_tiles;
  const int cam = ptile / PT_PER_CAM;
  const int pbase = (ptile % PT_PER_CAM) * PTILE;

  // B DMA setup: 2 instrs/wave, each covers 8 rows x 8 phys chunks
  const f16* gB[2]; int ldsoffB[2];
  const int clog = (ln & 7) ^ (ln >> 3);
  #pragma unroll
  for (int j = 0; j < 2; ++j) {
    int reg = j * 4 + wv;
    int r = reg * 8 + (ln >> 3);
    int pos = pbase + r;
    int hh = pos / WW, w2 = pos - hh * WW;
    gB[j] = X + ((long)((cam * PH + hh + 1) * PW + (w2 + 1))) * CIN_T + clog * 8;
    ldsoffB[j] = 16384 + reg * 1024;
  }

  // lane-constant bf addressing (bytes, within B region)
  const int base_l = (wn * 32 + lm) * 128;
  const int sx0 = ((0 * 4 + quad) ^ (lm & 7)) * 16;
  const int sx1 = ((1 * 4 + quad) ^ (lm & 7)) * 16;

  f32x4 acc[4][2];
  #pragma unroll
  for (int mi = 0; mi < 4; ++mi)
    #pragma unroll
    for (int ni = 0; ni < 2; ++ni)
      #pragma unroll
      for (int r = 0; r < 4; ++r) acc[mi][ni][r] = 0.f;

  auto choff = [&](int c) -> long {
    long off = 0;
    if (TAPS == 9) {
      int tp = c >> LCPT;
      int dy = tp / 3 - 1, dx = tp % 3 - 1;
      off = (long)(dy * PW + dx) * CIN_T;
    }
    return off + (long)(c & (CPT - 1)) * 64;
  };
  // stage one chunk's A (16KB: group0 8KB then group1 8KB) into buffer bsel
  auto stageA = [&](int bsel, int c) {
    const char* sb = (const char*)Wf + (long)c * 8192 + (long)ln * 16;
    char* db = S + bsel * 24576;
    #pragma unroll
    for (int j = 0; j < 4; ++j) {
      int seg = j * 4 + wv;                       // 0..15 (1KB segments)
      long gb = (long)(co_tile * 2 + (seg >> 3)) * GSTR;
      gl_lds16(sb + gb + (seg & 7) * 1024, db + seg * 1024);
    }
  };
  auto stageB = [&](int bsel, long curf) {
    #pragma unroll
    for (int j = 0; j < 2; ++j)
      gl_lds16(gB[j] + curf, S + bsel * 24576 + ldsoffB[j]);
  };
  auto compute = [&](int bsel) {
    const char* ab = S + bsel * 24576 + wm * 8192 + ln * 16;
    const char* bb = S + bsel * 24576 + 16384 + base_l;
    #pragma unroll
    for (int s = 0; s < 2; ++s) {
      f16x8 af[4];
      #pragma unroll
      for (int mi = 0; mi < 4; ++mi)
        af[mi] = *(const f16x8*)(ab + s * 4096 + mi * 1024);
      f16x8 bf[2];
      int sx = s ? sx1 : sx0;
      #pragma unroll
      for (int ni = 0; ni < 2; ++ni)
        bf[ni] = *(const f16x8*)(bb + ni * 2048 + sx);
      #pragma unroll
      for (int mi = 0; mi < 4; ++mi)
        #pragma unroll
        for (int ni = 0; ni < 2; ++ni)
          acc[mi][ni] = __builtin_amdgcn_mfma_f32_16x16x32_f16(af[mi], bf[ni], acc[mi][ni], 0, 0, 0);
    }
  };

  stageA(0, 0);
  stageB(0, choff(0));
  __syncthreads();

  #pragma unroll 1
  for (int c = 0; c < NCH; ++c) {
    int cur = c & 1;
    if (c + 1 < NCH) { stageA(cur ^ 1, c + 1); stageB(cur ^ 1, choff(c + 1)); }
    compute(cur);
    __syncthreads();
  }

  // ---- epilogue ----
  float4 b4[4], g4[4];
  bool skip[4];
  #pragma unroll
  for (int mi = 0; mi < 4; ++mi) {
    int co_l = wm * 64 + mi * 16 + quad * 4;
    int co_g = co_tile * 128 + co_l;
    skip[mi] = (MODE == 3) && (co_l >= DB);
    if (!skip[mi]) b4[mi] = *(const float4*)(bias + co_g);
    if (MODE == 0) g4[mi] = *(const float4*)(gate + cam * MIDC + co_g);
  }

  if (MODE == 3) {
    // fused depth softmax: stage logits to LDS [64 pos][116 bins], reduce 4 thr/pos.
    // (K-loop's final __syncthreads fences all LDS reads; S is reusable here.)
    float* P = (float*)S;
    #pragma unroll
    for (int ni = 0; ni < 2; ++ni) {
      int prow = wn * 32 + ni * 16 + lm;
      #pragma unroll
      for (int mi = 0; mi < 4; ++mi) {
        if (skip[mi]) continue;
        int co_l = wm * 64 + mi * 16 + quad * 4;
        float4 o;
        o.x = acc[mi][ni][0] + ((float*)&b4[mi])[0];
        o.y = acc[mi][ni][1] + ((float*)&b4[mi])[1];
        o.z = acc[mi][ni][2] + ((float*)&b4[mi])[2];
        o.w = acc[mi][ni][3] + ((float*)&b4[mi])[3];
        *(float4*)(P + prow * 116 + co_l) = o;
      }
    }
    __syncthreads();
    int p = t >> 2, k = t & 3;
    const float* Pr = P + p * 116;
    float m = -1e30f;
    for (int b = k; b < DB; b += 4) m = fmaxf(m, Pr[b]);
    m = fmaxf(m, __shfl_xor(m, 1));
    m = fmaxf(m, __shfl_xor(m, 2));
    float e[28];
    float ssum = 0.f;
    int cnt = 0;
    for (int b = k; b < DB; b += 4) { float ev = __expf(Pr[b] - m); e[cnt++] = ev; ssum += ev; }
    ssum += __shfl_xor(ssum, 1);
    ssum += __shfl_xor(ssum, 2);
    float inv = 1.f / ssum;
    float* op = Yf32 + ((long)(cam * NPOS + pbase + p)) * DB;
    cnt = 0;
    for (int b = k; b < DB; b += 4) op[b] = e[cnt++] * inv;
    return;
  }

  #pragma unroll
  for (int ni = 0; ni < 2; ++ni) {
    int pos = pbase + wn * 32 + ni * 16 + lm;
    int hh = pos / WW, w2 = pos - hh * WW;
    long ob = ((long)((cam * PH + hh + 1) * PW + (w2 + 1))) * MIDC + co_tile * 128;
    #pragma unroll
    for (int mi = 0; mi < 4; ++mi) {
      int co_l = wm * 64 + mi * 16 + quad * 4;
      float v[4];
      #pragma unroll
      for (int r = 0; r < 4; ++r) {
        float y = acc[mi][ni][r];
        y += ((float*)&b4[mi])[r];
        if (MODE == 0) y = fmaxf(y, 0.f) * ((float*)&g4[mi])[r];
        else if (MODE == 1) y = fmaxf(y, 0.f);
        v[r] = y;
      }
      if (MODE == 2) {
        f16x4 rv = *(const f16x4*)(res + ob + co_l);
        f16x4 o;
        #pragma unroll
        for (int r = 0; r < 4; ++r) o[r] = (f16)fmaxf(v[r] + (float)rv[r], 0.f);
        *(f16x4*)(Yf16 + ob + co_l) = o;
      } else {
        f16x4 o;
        #pragma unroll
        for (int r = 0; r < 4; ++r) o[r] = (f16)v[r];
        *(f16x4*)(Yf16 + ob + co_l) = o;
      }
    }
  }
}

// ---------------- trilinear grid sample + camera sum + normalize ----------------
// r10: clamped indices are ALWAYS in-bounds -> load unconditionally, mask only the
// WEIGHT (w=0 when tap invalid). Removes divergent guards around the 8 gathers so
// all loads issue under full exec mask and pipeline against L2 latency (dp is
// 12.6MB -> L2-resident). unroll 2 over cams -> 16 loads in flight.
__global__ void sample_kernel(const float* __restrict__ grid, const float* __restrict__ dp,
                              float* __restrict__ out) {
  int v = blockIdx.x * blockDim.x + threadIdx.x;
  if (v >= 128 * 128 * 16) return;
  int vz = v & 15, vy = (v >> 4) & 127, vx = v >> 11;
  float agg = 0.f, msk = 0.f;
  #pragma unroll 2
  for (int n = 0; n < NCAM; ++n) {
    long gb = ((long)((n * 128 + vx) * 128 + vy) * 16 + vz) * 3;
    float gx = grid[gb], gy = grid[gb + 1], gz = grid[gb + 2];
    float ix = ((gx + 1.f) * (float)WW - 1.f) * 0.5f;
    float iy = ((gy + 1.f) * (float)HH - 1.f) * 0.5f;
    float iz = ((gz + 1.f) * (float)DB - 1.f) * 0.5f;
    float xf = floorf(ix), yf = floorf(iy), zf = floorf(iz);
    float fx = ix - xf, fy = iy - yf, fz = iz - zf;
    int x0 = (int)xf, y0 = (int)yf, z0 = (int)zf;
    const float* dpn = dp + (long)n * HH * WW * DB;
    float wx[2] = {1.f - fx, fx};
    float wy[2] = {1.f - fy, fy};
    float wz[2] = {1.f - fz, fz};
    int xc[2], yc[2], zc[2];
    bool xv[2], yv[2], zv[2];
    #pragma unroll
    for (int d = 0; d < 2; ++d) {
      int x = x0 + d; xv[d] = (x >= 0) && (x < WW); xc[d] = x < 0 ? 0 : (x > WW - 1 ? WW - 1 : x);
      int y = y0 + d; yv[d] = (y >= 0) && (y < HH); yc[d] = y < 0 ? 0 : (y > HH - 1 ? HH - 1 : y);
      int z = z0 + d; zv[d] = (z >= 0) && (z < DB); zc[d] = z < 0 ? 0 : (z > DB - 1 ? DB - 1 : z);
    }
    #pragma unroll
    for (int dy2 = 0; dy2 < 2; ++dy2) {
      #pragma unroll
      for (int dx2 = 0; dx2 < 2; ++dx2) {
        const float* base = dpn + ((long)(yc[dy2] * WW + xc[dx2])) * DB;
        float d0 = base[zc[0]];
        float d1 = base[zc[1]];
        float wxy = wx[dx2] * wy[dy2];
        bool vv = xv[dx2] && yv[dy2];
        float w0 = (vv && zv[0]) ? wxy * wz[0] : 0.f;
        float w1 = (vv && zv[1]) ? wxy * wz[1] : 0.f;
        msk += w0 + w1;
        agg += w0 * d0 + w1 * d1;
      }
    }
  }
  out[v] = (msk > 0.f) ? (agg / msk) : agg;
}

extern "C" void kernel_launch(void* const* d_in, const int* in_sizes, int n_in,
                              void* d_out, int out_size, void* d_ws, size_t ws_size,
                              hipStream_t stream) {
  const float* img   = (const float*)d_in[0];
  const float* intr  = (const float*)d_in[1];
  const float* grid  = (const float*)d_in[2];
  const float* red_w = (const float*)d_in[3];
  const float* red_s = (const float*)d_in[4];
  const float* red_b = (const float*)d_in[5];
  const float* w1    = (const float*)d_in[6];
  const float* b1    = (const float*)d_in[7];
  const float* w2    = (const float*)d_in[8];
  const float* b2    = (const float*)d_in[9];
  const float* rw    = (const float*)d_in[10];
  const float* rb    = (const float*)d_in[11];
  const float* ew    = (const float*)d_in[12];
  const float* eb    = (const float*)d_in[13];
  const float* bb_w  = (const float*)d_in[14];
  const float* bb_s  = (const float*)d_in[15];
  const float* bb_b  = (const float*)d_in[16];
  const float* dp_w  = (const float*)d_in[17];
  const float* dp_b  = (const float*)d_in[18];
  float* out = (float*)d_out;

  char* ws = (char*)d_ws;
  float* gate = (float*)(ws + O_GATE);
  f16* wfred  = (f16*)(ws + O_WFRED);
  f16* wfbb   = (f16*)(ws + O_WFBB);
  f16* wfdp   = (f16*)(ws + O_WFDP);
  f16* xp0    = (f16*)(ws + O_XP0);
  f16* X1     = (f16*)(ws + O_X1);
  f16* X2     = (f16*)(ws + O_X2);
  f16* X3     = (f16*)(ws + O_X3);
  float* dpb  = (float*)(ws + O_DP);

  prep_kernel<<<11097, 256, 0, stream>>>(xp0, X1, X2, X3, img,
                                         intr, w1, b1, w2, b2, rw, rb, ew, eb, gate,
                                         red_w, red_s, wfred, bb_w, bb_s, wfbb, dp_w, wfdp);

  const long WCH = 4L * 9 * 8 * 2048;  // per-conv fragment-weight stride (f16)

  conv_mfma<0, 512, 9><<<528, 256, 0, stream>>>(xp0, wfred, red_b, gate, nullptr, X1, nullptr, 2);

  conv_mfma<1, 256, 9><<<528, 256, 0, stream>>>(X1, wfbb + 0 * WCH, bb_b + 0 * 256, nullptr, nullptr, X2, nullptr, 2);
  conv_mfma<2, 256, 9><<<528, 256, 0, stream>>>(X2, wfbb + 1 * WCH, bb_b + 1 * 256, nullptr, X1, X3, nullptr, 2);
  conv_mfma<1, 256, 9><<<528, 256, 0, stream>>>(X3, wfbb + 2 * WCH, bb_b + 2 * 256, nullptr, nullptr, X2, nullptr, 2);
  conv_mfma<2, 256, 9><<<528, 256, 0, stream>>>(X2, wfbb + 3 * WCH, bb_b + 3 * 256, nullptr, X3, X1, nullptr, 2);
  conv_mfma<1, 256, 9><<<528, 256, 0, stream>>>(X1, wfbb + 4 * WCH, bb_b + 4 * 256, nullptr, nullptr, X2, nullptr, 2);
  conv_mfma<2, 256, 9><<<528, 256, 0, stream>>>(X2, wfbb + 5 * WCH, bb_b + 5 * 256, nullptr, X1, X3, nullptr, 2);

  // dp conv with fused softmax -> writes normalized dp directly
  conv_mfma<3, 256, 1><<<264, 256, 0, stream>>>(X3, wfdp, dp_b, nullptr, nullptr, nullptr, dpb, 1);

  sample_kernel<<<1024, 256, 0, stream>>>(grid, dpb, out);
}